// Round 6
// baseline (305.388 us; speedup 1.0000x reference)
//
#include <hip/hip_runtime.h>
#include <hip/hip_bf16.h>
#include <stdint.h>

#define B_ 2
#define S_ 2048
#define D_ 2048
#define H_ 32
#define KV_ 8
#define HD_ 64
#define NQKV 3072   // D + 2*KV*HD

typedef __bf16 bf16_t;
typedef __bf16 bf16x8 __attribute__((ext_vector_type(8)));
typedef __bf16 bf16x4 __attribute__((ext_vector_type(4)));
typedef float  f32x4  __attribute__((ext_vector_type(4)));
typedef float  f32x16 __attribute__((ext_vector_type(16)));
typedef unsigned int u32;
typedef u32 u32x4 __attribute__((ext_vector_type(4)));

typedef const __attribute__((address_space(1))) uint32_t* gp1_t;
typedef __attribute__((address_space(3))) uint32_t* lp3_t;

// async global->LDS, 16B per lane. LDS dest is wave-uniform base + lane*16.
__device__ inline void gload_lds16(const void* g, void* l) {
  __builtin_amdgcn_global_load_lds((gp1_t)(uintptr_t)g, (lp3_t)(uint32_t)(uintptr_t)l,
                                   16, 0, 0);
}

__device__ inline u32 pkbf(float a, float b) {
  union { bf16_t h[2]; u32 u; } v;
  v.h[0] = (bf16_t)a; v.h[1] = (bf16_t)b;
  return v.u;
}

// v_permlane32_swap_b32: a = [a_lo, b_lo], b = [a_hi, b_hi]
__device__ inline void pl32swap(u32 &a, u32 &b) {
  asm("v_permlane32_swap_b32 %0, %1" : "+v"(a), "+v"(b));
}

// ---------------- converts ----------------
__global__ void cvt_f32_bf16(const float* __restrict__ in, bf16_t* __restrict__ out, int n4) {
  int i = blockIdx.x * blockDim.x + threadIdx.x;
  if (i < n4) {
    float4 v = ((const float4*)in)[i];
    bf16x4 o;
    o[0] = (bf16_t)v.x; o[1] = (bf16_t)v.y; o[2] = (bf16_t)v.z; o[3] = (bf16_t)v.w;
    ((bf16x4*)out)[i] = o;
  }
}

// transpose + cast: out[row_off + c][r] = in[r][c]
__global__ void transpose_cvt(const float* __restrict__ in, bf16_t* __restrict__ out,
                              int C, int row_off) {
  __shared__ float t[32][33];
  int tx = threadIdx.x, ty = threadIdx.y;       // (32,8)
  int c0 = blockIdx.x * 32, r0 = blockIdx.y * 32;
#pragma unroll
  for (int j = 0; j < 4; ++j)
    t[ty + j*8][tx] = in[(int64_t)(r0 + ty + j*8) * C + c0 + tx];
  __syncthreads();
#pragma unroll
  for (int j = 0; j < 4; ++j)
    out[(int64_t)(row_off + c0 + ty + j*8) * 2048 + r0 + tx] = (bf16_t)t[tx][ty + j*8];
}

// Vbuf[b][s][cc] -> Vt[b][cc][s]  (LDS-tiled transpose, coalesced both sides)
__global__ void v_transpose(const bf16_t* __restrict__ Vbuf, bf16_t* __restrict__ Vt) {
  __shared__ bf16_t t[32][34];
  const int tx = threadIdx.x, ty = threadIdx.y;   // (32,8)
  const int c0 = blockIdx.x * 32;                 // cc within 512
  const int s0 = blockIdx.y * 32;
  const int b  = blockIdx.z;
#pragma unroll
  for (int j = 0; j < 4; ++j)
    t[ty + j*8][tx] = Vbuf[(int64_t)(b * S_ + s0 + ty + j*8) * 512 + c0 + tx];
  __syncthreads();
#pragma unroll
  for (int j = 0; j < 4; ++j)
    Vt[(int64_t)(b * 512 + c0 + ty + j*8) * S_ + s0 + tx] = t[tx][ty + j*8];
}

// ---------------- plain GEMM: C = A @ B, Bt = B^T (N x K) ----------------
template <typename OutT>
__global__ __launch_bounds__(256) void gemm_bt(const bf16_t* __restrict__ A,
                                               const bf16_t* __restrict__ Bt,
                                               OutT* __restrict__ C,
                                               int M, int N, int K) {
  __shared__ bf16_t As[128 * 32];
  __shared__ bf16_t Bs[128 * 32];
  const int tid = threadIdx.x;
  const int wid = tid >> 6, lane = tid & 63;
  const int l15 = lane & 15, l4 = lane >> 4;
  const int bm = blockIdx.y * 128, bn = blockIdx.x * 128;
  const int wm = (wid >> 1) * 64, wn = (wid & 1) * 64;

  f32x4 acc[4][4] = {};

  const int arow0 = tid >> 2;
  const int kslot = (tid & 3) * 8;
  const bf16_t* Ag0 = A  + (int64_t)(bm + arow0)      * K + kslot;
  const bf16_t* Ag1 = A  + (int64_t)(bm + arow0 + 64) * K + kslot;
  const bf16_t* Bg0 = Bt + (int64_t)(bn + arow0)      * K + kslot;
  const bf16_t* Bg1 = Bt + (int64_t)(bn + arow0 + 64) * K + kslot;
  char* AsB = (char*)As + wid * 1024;
  char* BsB = (char*)Bs + wid * 1024;

  for (int k0 = 0; k0 < K; k0 += 32) {
    gload_lds16(Ag0 + k0, AsB);
    gload_lds16(Ag1 + k0, AsB + 4096);
    gload_lds16(Bg0 + k0, BsB);
    gload_lds16(Bg1 + k0, BsB + 4096);
    asm volatile("s_waitcnt vmcnt(0)" ::: "memory");
    __syncthreads();

    bf16x8 af[4], bfr[4];
#pragma unroll
    for (int m = 0; m < 4; ++m)
      af[m] = *(const bf16x8*)(As + (wm + m*16 + l15) * 32 + l4 * 8);
#pragma unroll
    for (int n = 0; n < 4; ++n)
      bfr[n] = *(const bf16x8*)(Bs + (wn + n*16 + l15) * 32 + l4 * 8);
#pragma unroll
    for (int m = 0; m < 4; ++m)
#pragma unroll
      for (int n = 0; n < 4; ++n)
        acc[m][n] = __builtin_amdgcn_mfma_f32_16x16x32_bf16(af[m], bfr[n], acc[m][n], 0, 0, 0);
    __syncthreads();
  }

#pragma unroll
  for (int m = 0; m < 4; ++m) {
    const int row = bm + wm + m*16 + l4*4;
#pragma unroll
    for (int n = 0; n < 4; ++n) {
      const int col = bn + wn + n*16 + l15;
#pragma unroll
      for (int r = 0; r < 4; ++r)
        C[(int64_t)(row + r) * N + col] = (OutT)acc[m][n][r];
    }
  }
}

// ---------------- QKV GEMM with fused RoPE / scatter ----------------
// A: (B*S) x 2048 bf16 (x). Bt: 3072 x 2048 bf16 ([Wq|Wk|Wv]^T).
// Epilogue: cols [0,2048)    -> RoPE*QSCALE -> Q[b][h][s][d]
//           cols [2048,2560) -> RoPE        -> Kr[b][kvh][s][d]
//           cols [2560,3072) -> Vbuf[b][s][cc] (row-major, coalesced)
// A wave's 64-col span lies in one head; RoPE partner d^32 is acc[m][n^2][r] (same lane).
#define QSCALE 0.18033688011112042f
__global__ __launch_bounds__(256) void gemm_qkv(const bf16_t* __restrict__ A,
                                                const bf16_t* __restrict__ Bt,
                                                const float* __restrict__ cosb,
                                                const float* __restrict__ sinb,
                                                bf16_t* __restrict__ Q,
                                                bf16_t* __restrict__ Kr,
                                                bf16_t* __restrict__ Vbuf) {
  constexpr int K = 2048;
  __shared__ bf16_t As[128 * 32];
  __shared__ bf16_t Bs[128 * 32];
  const int tid = threadIdx.x;
  const int wid = tid >> 6, lane = tid & 63;
  const int l15 = lane & 15, l4 = lane >> 4;
  const int bm = blockIdx.y * 128, bn = blockIdx.x * 128;
  const int wm = (wid >> 1) * 64, wn = (wid & 1) * 64;

  f32x4 acc[4][4] = {};

  const int arow0 = tid >> 2;
  const int kslot = (tid & 3) * 8;
  const bf16_t* Ag0 = A  + (int64_t)(bm + arow0)      * K + kslot;
  const bf16_t* Ag1 = A  + (int64_t)(bm + arow0 + 64) * K + kslot;
  const bf16_t* Bg0 = Bt + (int64_t)(bn + arow0)      * K + kslot;
  const bf16_t* Bg1 = Bt + (int64_t)(bn + arow0 + 64) * K + kslot;
  char* AsB = (char*)As + wid * 1024;
  char* BsB = (char*)Bs + wid * 1024;

  for (int k0 = 0; k0 < K; k0 += 32) {
    gload_lds16(Ag0 + k0, AsB);
    gload_lds16(Ag1 + k0, AsB + 4096);
    gload_lds16(Bg0 + k0, BsB);
    gload_lds16(Bg1 + k0, BsB + 4096);
    asm volatile("s_waitcnt vmcnt(0)" ::: "memory");
    __syncthreads();

    bf16x8 af[4], bfr[4];
#pragma unroll
    for (int m = 0; m < 4; ++m)
      af[m] = *(const bf16x8*)(As + (wm + m*16 + l15) * 32 + l4 * 8);
#pragma unroll
    for (int n = 0; n < 4; ++n)
      bfr[n] = *(const bf16x8*)(Bs + (wn + n*16 + l15) * 32 + l4 * 8);
#pragma unroll
    for (int m = 0; m < 4; ++m)
#pragma unroll
      for (int n = 0; n < 4; ++n)
        acc[m][n] = __builtin_amdgcn_mfma_f32_16x16x32_bf16(af[m], bfr[n], acc[m][n], 0, 0, 0);
    __syncthreads();
  }

  const int colbase = bn + wn;            // multiple of 64 -> wave-uniform region/head
  if (colbase < 2048) {                   // -------- Q region (RoPE + scale) --------
    const int h = colbase >> 6;
#pragma unroll
    for (int m = 0; m < 4; ++m) {
#pragma unroll
      for (int r = 0; r < 4; ++r) {
        const int srow = bm + wm + m*16 + l4*4 + r;
        const int b = srow >> 11, s = srow & 2047;
        const float* cs = cosb + s * HD_;
        const float* sn = sinb + s * HD_;
        bf16_t* qp = Q + ((int64_t)(b * H_ + h) * S_ + s) * HD_;
#pragma unroll
        for (int n = 0; n < 4; ++n) {
          const int d = n*16 + l15;
          const float sgn = (n & 2) ? 1.f : -1.f;
          float o = (acc[m][n][r] * cs[d] + sgn * acc[m][n^2][r] * sn[d]) * QSCALE;
          qp[d] = (bf16_t)o;
        }
      }
    }
  } else if (colbase < 2560) {            // -------- K region (RoPE) --------
    const int kvh = (colbase - 2048) >> 6;
#pragma unroll
    for (int m = 0; m < 4; ++m) {
#pragma unroll
      for (int r = 0; r < 4; ++r) {
        const int srow = bm + wm + m*16 + l4*4 + r;
        const int b = srow >> 11, s = srow & 2047;
        const float* cs = cosb + s * HD_;
        const float* sn = sinb + s * HD_;
        bf16_t* kp = Kr + ((int64_t)(b * KV_ + kvh) * S_ + s) * HD_;
#pragma unroll
        for (int n = 0; n < 4; ++n) {
          const int d = n*16 + l15;
          const float sgn = (n & 2) ? 1.f : -1.f;
          float o = acc[m][n][r] * cs[d] + sgn * acc[m][n^2][r] * sn[d];
          kp[d] = (bf16_t)o;
        }
      }
    }
  } else {                                // -------- V region (row-major, coalesced) --------
    const int ccb = colbase - 2560;
#pragma unroll
    for (int m = 0; m < 4; ++m) {
#pragma unroll
      for (int r = 0; r < 4; ++r) {
        const int srow = bm + wm + m*16 + l4*4 + r;
        bf16_t* vp = Vbuf + (int64_t)srow * 512 + ccb;
#pragma unroll
        for (int n = 0; n < 4; ++n)
          vp[n*16 + l15] = (bf16_t)acc[m][n][r];
      }
    }
  }
}

// ---------------- flash attention: per-block KV-split across 4 waves ----------------
// grid (64 = h + 32*b, 64 = qc). Block 256 thr = 4 waves, all share the SAME 32 q-rows;
// wave w handles kv-tiles t = w, w+4, ... (no barriers in main loop). Static-shift
// softmax makes partials addable: combine O-partials + l-partials in LDS at the end.
#define SHIFT_ 8.0f
__global__ __launch_bounds__(256, 4) void attn4(const bf16_t* __restrict__ Q,
                                                const bf16_t* __restrict__ Kr,
                                                const bf16_t* __restrict__ Vt,
                                                bf16_t* __restrict__ AO) {
  const int hb = blockIdx.x;
  const int h = hb & 31, b = hb >> 5;
  const int qc = 63 - (int)blockIdx.y;    // LPT: longest blocks first
  const int tid = threadIdx.x;
  const int w = tid >> 6, lane = tid & 63;
  const int l31 = lane & 31, hi = lane >> 5;
  const int kvh = h >> 2;                 // NREP = 4
  const int q0 = qc * 32;

  const bf16_t* Qb = Q  + ((int64_t)(b * H_ + h) * S_ + q0) * HD_;
  const bf16_t* Kb = Kr + (int64_t)(b * KV_ + kvh) * S_ * HD_;
  const bf16_t* Vb = Vt + (int64_t)(b * KV_ + kvh) * HD_ * S_;

  bf16x8 qf[4];
#pragma unroll
  for (int ds = 0; ds < 4; ++ds)
    qf[ds] = *(const bf16x8*)(Qb + l31 * HD_ + ds * 16 + hi * 8);

  f32x16 accO0 = {}, accO1 = {};          // O^T partial: rows d 0-31 / 32-63, col q = l31
  float lhalf = 0.f;
  const int NT = qc + 1;                  // kv tiles of 32; tile NT-1 is diagonal

  auto qk = [&](int kv0) -> f32x16 {
    f32x16 s = {};
    __builtin_amdgcn_s_setprio(1);
#pragma unroll
    for (int ds = 0; ds < 4; ++ds) {
      bf16x8 kf = *(const bf16x8*)(Kb + (int64_t)(kv0 + l31) * HD_ + ds * 16 + hi * 8);
      s = __builtin_amdgcn_mfma_f32_32x32x16_bf16(kf, qf[ds], s, 0, 0, 0);
    }
    __builtin_amdgcn_s_setprio(0);
    return s;
  };

  auto softmax_pf = [&](const f32x16 &sacc, bool maskdiag, bf16x8 &pf0, bf16x8 &pf1) {
    float p[16];
#pragma unroll
    for (int r = 0; r < 16; ++r) {
      float sc = sacc[r];
      if (maskdiag) {
        int kvpos = (r & 3) + 8 * (r >> 2) + 4 * hi;
        if (kvpos > l31) sc = -1e30f;
      }
      p[r] = __builtin_amdgcn_exp2f(sc - SHIFT_);
    }
    float t0 = (p[0] + p[1]) + (p[2] + p[3]);
    float t1 = (p[4] + p[5]) + (p[6] + p[7]);
    float t2 = (p[8] + p[9]) + (p[10] + p[11]);
    float t3 = (p[12] + p[13]) + (p[14] + p[15]);
    lhalf += (t0 + t1) + (t2 + t3);
    u32 pk[8];
#pragma unroll
    for (int i = 0; i < 8; ++i) pk[i] = pkbf(p[2*i], p[2*i+1]);
    u32 a0 = pk[0], b0 = pk[2]; pl32swap(a0, b0);
    u32 a1 = pk[1], b1 = pk[3]; pl32swap(a1, b1);
    u32 a2 = pk[4], b2 = pk[6]; pl32swap(a2, b2);
    u32 a3 = pk[5], b3 = pk[7]; pl32swap(a3, b3);
    pf0 = __builtin_bit_cast(bf16x8, (u32x4){a0, a1, b0, b1});
    pf1 = __builtin_bit_cast(bf16x8, (u32x4){a2, a3, b2, b3});
  };

  auto pv = [&](int kv0, bf16x8 pf0, bf16x8 pf1) {
    bf16x8 v00 = *(const bf16x8*)(Vb + (int64_t)l31 * S_ + kv0 + hi * 8);
    bf16x8 v01 = *(const bf16x8*)(Vb + (int64_t)l31 * S_ + kv0 + 16 + hi * 8);
    bf16x8 v10 = *(const bf16x8*)(Vb + (int64_t)(32 + l31) * S_ + kv0 + hi * 8);
    bf16x8 v11 = *(const bf16x8*)(Vb + (int64_t)(32 + l31) * S_ + kv0 + 16 + hi * 8);
    __builtin_amdgcn_s_setprio(1);
    accO0 = __builtin_amdgcn_mfma_f32_32x32x16_bf16(v00, pf0, accO0, 0, 0, 0);
    accO1 = __builtin_amdgcn_mfma_f32_32x32x16_bf16(v10, pf0, accO1, 0, 0, 0);
    accO0 = __builtin_amdgcn_mfma_f32_32x32x16_bf16(v01, pf1, accO0, 0, 0, 0);
    accO1 = __builtin_amdgcn_mfma_f32_32x32x16_bf16(v11, pf1, accO1, 0, 0, 0);
    __builtin_amdgcn_s_setprio(0);
  };

  int t = w;
  for (; t + 8 <= NT; t += 8) {           // paired independent tiles (never diagonal)
    f32x16 sA = qk(t * 32);
    f32x16 sB = qk((t + 4) * 32);
    bf16x8 pA0, pA1, pB0, pB1;
    softmax_pf(sA, false, pA0, pA1);
    softmax_pf(sB, false, pB0, pB1);
    pv(t * 32, pA0, pA1);
    pv((t + 4) * 32, pB0, pB1);
  }
  for (; t < NT; t += 4) {                // remainder (may include diagonal)
    f32x16 sA = qk(t * 32);
    bf16x8 pA0, pA1;
    softmax_pf(sA, t == NT - 1, pA0, pA1);
    pv(t * 32, pA0, pA1);
  }

  // ---- combine partials across the 4 waves ----
  __shared__ float Of[4][32][64];
  __shared__ float Lw[4][32];
  float lw = lhalf + __shfl_xor(lhalf, 32);
  if (lane < 32) Lw[w][lane] = lw;
#pragma unroll
  for (int dt = 0; dt < 2; ++dt)
#pragma unroll
    for (int r = 0; r < 16; ++r) {
      const int d = dt * 32 + (r & 3) + 8 * (r >> 2) + 4 * hi;
      Of[w][l31][d] = dt ? accO1[r] : accO0[r];
    }
  __syncthreads();

  const int ql = w * 8 + (lane >> 3);     // 0..31
  const int d0 = (lane & 7) * 8;
  f32x4 s0 = {}, s1 = {};
  float ltot = 0.f;
#pragma unroll
  for (int wv = 0; wv < 4; ++wv) {
    s0 += *(const f32x4*)&Of[wv][ql][d0];
    s1 += *(const f32x4*)&Of[wv][ql][d0 + 4];
    ltot += Lw[wv][ql];
  }
  const float rl = 1.f / ltot;
  bf16x8 ov;
#pragma unroll
  for (int j = 0; j < 4; ++j) {
    ov[j]     = (bf16_t)(s0[j] * rl);
    ov[4 + j] = (bf16_t)(s1[j] * rl);
  }
  const int64_t row = (int64_t)(b * S_ + q0 + ql);
  *(bf16x8*)(AO + row * D_ + h * HD_ + d0) = ov;
}

// ---------------- launcher ----------------
extern "C" void kernel_launch(void* const* d_in, const int* in_sizes, int n_in,
                              void* d_out, int out_size, void* d_ws, size_t ws_size,
                              hipStream_t stream) {
  const float* x    = (const float*)d_in[0];
  const float* cosb = (const float*)d_in[1];
  const float* sinb = (const float*)d_in[2];
  const float* Wq   = (const float*)d_in[3];
  const float* Wk   = (const float*)d_in[4];
  const float* Wv   = (const float*)d_in[5];
  const float* Wo   = (const float*)d_in[6];
  float* out = (float*)d_out;

  bf16_t* ws = (bf16_t*)d_ws;
  size_t o = 0;
  bf16_t* xb    = ws + o; o += (size_t)4096 * 2048;
  bf16_t* Wqkvt = ws + o; o += (size_t)3072 * 2048;
  bf16_t* Wot   = ws + o; o += (size_t)2048 * 2048;
  bf16_t* Qr    = ws + o; o += (size_t)B_ * H_ * S_ * HD_;
  bf16_t* Krb   = ws + o; o += (size_t)B_ * KV_ * S_ * HD_;
  bf16_t* Vtb   = ws + o; o += (size_t)B_ * KV_ * S_ * HD_;
  bf16_t* Vbuf  = ws + o; o += (size_t)B_ * S_ * 512;
  bf16_t* AO    = ws + o; o += (size_t)4096 * 2048;

  cvt_f32_bf16<<<(8388608/4 + 255)/256, 256, 0, stream>>>(x, xb, 8388608/4);
  transpose_cvt<<<dim3(2048/32, 2048/32), dim3(32, 8), 0, stream>>>(Wq, Wqkvt, 2048, 0);
  transpose_cvt<<<dim3(512/32, 2048/32),  dim3(32, 8), 0, stream>>>(Wk, Wqkvt, 512, 2048);
  transpose_cvt<<<dim3(512/32, 2048/32),  dim3(32, 8), 0, stream>>>(Wv, Wqkvt, 512, 2560);
  transpose_cvt<<<dim3(2048/32, 2048/32), dim3(32, 8), 0, stream>>>(Wo, Wot, 2048, 0);
  // fused QKV projection + RoPE + scatter (V row-major)
  gemm_qkv<<<dim3(3072/128, 4096/128), 256, 0, stream>>>(xb, Wqkvt, cosb, sinb, Qr, Krb, Vbuf);
  // V transpose to [b][d][s]
  v_transpose<<<dim3(16, 64, 2), dim3(32, 8), 0, stream>>>(Vbuf, Vtb);
  // causal GQA attention, KV-split across 4 waves per block
  attn4<<<dim3(64, 64), 256, 0, stream>>>(Qr, Krb, Vtb, AO);
  // output projection -> f32
  gemm_bt<float><<<dim3(2048/128, 4096/128), 256, 0, stream>>>(AO, Wot, out, 4096, 2048, 2048);
}

// Round 7
// 236.999 us; speedup vs baseline: 1.2886x; 1.2886x over previous
//
#include <hip/hip_runtime.h>
#include <hip/hip_bf16.h>
#include <stdint.h>

#define B_ 2
#define S_ 2048
#define D_ 2048
#define H_ 32
#define KV_ 8
#define HD_ 64
#define NQKV 3072   // D + 2*KV*HD

typedef __bf16 bf16_t;
typedef __bf16 bf16x8 __attribute__((ext_vector_type(8)));
typedef __bf16 bf16x4 __attribute__((ext_vector_type(4)));
typedef float  f32x4  __attribute__((ext_vector_type(4)));
typedef float  f32x16 __attribute__((ext_vector_type(16)));
typedef unsigned int u32;
typedef u32 u32x4 __attribute__((ext_vector_type(4)));

typedef const __attribute__((address_space(1))) uint32_t* gp1_t;
typedef __attribute__((address_space(3))) uint32_t* lp3_t;

// async global->LDS, 16B per lane. LDS dest is wave-uniform base + lane*16.
__device__ inline void gload_lds16(const void* g, void* l) {
  __builtin_amdgcn_global_load_lds((gp1_t)(uintptr_t)g, (lp3_t)(uint32_t)(uintptr_t)l,
                                   16, 0, 0);
}

__device__ inline u32 pkbf(float a, float b) {
  union { bf16_t h[2]; u32 u; } v;
  v.h[0] = (bf16_t)a; v.h[1] = (bf16_t)b;
  return v.u;
}

// v_permlane32_swap_b32: a = [a_lo, b_lo], b = [a_hi, b_hi]
__device__ inline void pl32swap(u32 &a, u32 &b) {
  asm("v_permlane32_swap_b32 %0, %1" : "+v"(a), "+v"(b));
}

// ---------------- converts ----------------
__global__ void cvt_f32_bf16(const float* __restrict__ in, bf16_t* __restrict__ out, int n4) {
  int i = blockIdx.x * blockDim.x + threadIdx.x;
  if (i < n4) {
    float4 v = ((const float4*)in)[i];
    bf16x4 o;
    o[0] = (bf16_t)v.x; o[1] = (bf16_t)v.y; o[2] = (bf16_t)v.z; o[3] = (bf16_t)v.w;
    ((bf16x4*)out)[i] = o;
  }
}

// transpose + cast: out[row_off + c][r] = in[r][c]
__global__ void transpose_cvt(const float* __restrict__ in, bf16_t* __restrict__ out,
                              int C, int row_off) {
  __shared__ float t[32][33];
  int tx = threadIdx.x, ty = threadIdx.y;       // (32,8)
  int c0 = blockIdx.x * 32, r0 = blockIdx.y * 32;
#pragma unroll
  for (int j = 0; j < 4; ++j)
    t[ty + j*8][tx] = in[(int64_t)(r0 + ty + j*8) * C + c0 + tx];
  __syncthreads();
#pragma unroll
  for (int j = 0; j < 4; ++j)
    out[(int64_t)(row_off + c0 + ty + j*8) * 2048 + r0 + tx] = (bf16_t)t[tx][ty + j*8];
}

// Vbuf[b][s][cc] -> Vt[b][cc][s]  (LDS-tiled transpose, coalesced both sides)
__global__ void v_transpose(const bf16_t* __restrict__ Vbuf, bf16_t* __restrict__ Vt) {
  __shared__ bf16_t t[32][34];
  const int tx = threadIdx.x, ty = threadIdx.y;   // (32,8)
  const int c0 = blockIdx.x * 32;                 // cc within 512
  const int s0 = blockIdx.y * 32;
  const int b  = blockIdx.z;
#pragma unroll
  for (int j = 0; j < 4; ++j)
    t[ty + j*8][tx] = Vbuf[(int64_t)(b * S_ + s0 + ty + j*8) * 512 + c0 + tx];
  __syncthreads();
#pragma unroll
  for (int j = 0; j < 4; ++j)
    Vt[(int64_t)(b * 512 + c0 + ty + j*8) * S_ + s0 + tx] = t[tx][ty + j*8];
}

// ---------------- plain GEMM: C = A @ B, Bt = B^T (N x K) ----------------
template <typename OutT>
__global__ __launch_bounds__(256) void gemm_bt(const bf16_t* __restrict__ A,
                                               const bf16_t* __restrict__ Bt,
                                               OutT* __restrict__ C,
                                               int M, int N, int K) {
  __shared__ bf16_t As[128 * 32];
  __shared__ bf16_t Bs[128 * 32];
  const int tid = threadIdx.x;
  const int wid = tid >> 6, lane = tid & 63;
  const int l15 = lane & 15, l4 = lane >> 4;
  const int bm = blockIdx.y * 128, bn = blockIdx.x * 128;
  const int wm = (wid >> 1) * 64, wn = (wid & 1) * 64;

  f32x4 acc[4][4] = {};

  const int arow0 = tid >> 2;
  const int kslot = (tid & 3) * 8;
  const bf16_t* Ag0 = A  + (int64_t)(bm + arow0)      * K + kslot;
  const bf16_t* Ag1 = A  + (int64_t)(bm + arow0 + 64) * K + kslot;
  const bf16_t* Bg0 = Bt + (int64_t)(bn + arow0)      * K + kslot;
  const bf16_t* Bg1 = Bt + (int64_t)(bn + arow0 + 64) * K + kslot;
  char* AsB = (char*)As + wid * 1024;
  char* BsB = (char*)Bs + wid * 1024;

  for (int k0 = 0; k0 < K; k0 += 32) {
    gload_lds16(Ag0 + k0, AsB);
    gload_lds16(Ag1 + k0, AsB + 4096);
    gload_lds16(Bg0 + k0, BsB);
    gload_lds16(Bg1 + k0, BsB + 4096);
    asm volatile("s_waitcnt vmcnt(0)" ::: "memory");
    __syncthreads();

    bf16x8 af[4], bfr[4];
#pragma unroll
    for (int m = 0; m < 4; ++m)
      af[m] = *(const bf16x8*)(As + (wm + m*16 + l15) * 32 + l4 * 8);
#pragma unroll
    for (int n = 0; n < 4; ++n)
      bfr[n] = *(const bf16x8*)(Bs + (wn + n*16 + l15) * 32 + l4 * 8);
#pragma unroll
    for (int m = 0; m < 4; ++m)
#pragma unroll
      for (int n = 0; n < 4; ++n)
        acc[m][n] = __builtin_amdgcn_mfma_f32_16x16x32_bf16(af[m], bfr[n], acc[m][n], 0, 0, 0);
    __syncthreads();
  }

#pragma unroll
  for (int m = 0; m < 4; ++m) {
    const int row = bm + wm + m*16 + l4*4;
#pragma unroll
    for (int n = 0; n < 4; ++n) {
      const int col = bn + wn + n*16 + l15;
#pragma unroll
      for (int r = 0; r < 4; ++r)
        C[(int64_t)(row + r) * N + col] = (OutT)acc[m][n][r];
    }
  }
}

// ---------------- QKV GEMM with fused RoPE / scatter ----------------
#define QSCALE 0.18033688011112042f
__global__ __launch_bounds__(256) void gemm_qkv(const bf16_t* __restrict__ A,
                                                const bf16_t* __restrict__ Bt,
                                                const float* __restrict__ cosb,
                                                const float* __restrict__ sinb,
                                                bf16_t* __restrict__ Q,
                                                bf16_t* __restrict__ Kr,
                                                bf16_t* __restrict__ Vbuf) {
  constexpr int K = 2048;
  __shared__ bf16_t As[128 * 32];
  __shared__ bf16_t Bs[128 * 32];
  const int tid = threadIdx.x;
  const int wid = tid >> 6, lane = tid & 63;
  const int l15 = lane & 15, l4 = lane >> 4;
  const int bm = blockIdx.y * 128, bn = blockIdx.x * 128;
  const int wm = (wid >> 1) * 64, wn = (wid & 1) * 64;

  f32x4 acc[4][4] = {};

  const int arow0 = tid >> 2;
  const int kslot = (tid & 3) * 8;
  const bf16_t* Ag0 = A  + (int64_t)(bm + arow0)      * K + kslot;
  const bf16_t* Ag1 = A  + (int64_t)(bm + arow0 + 64) * K + kslot;
  const bf16_t* Bg0 = Bt + (int64_t)(bn + arow0)      * K + kslot;
  const bf16_t* Bg1 = Bt + (int64_t)(bn + arow0 + 64) * K + kslot;
  char* AsB = (char*)As + wid * 1024;
  char* BsB = (char*)Bs + wid * 1024;

  for (int k0 = 0; k0 < K; k0 += 32) {
    gload_lds16(Ag0 + k0, AsB);
    gload_lds16(Ag1 + k0, AsB + 4096);
    gload_lds16(Bg0 + k0, BsB);
    gload_lds16(Bg1 + k0, BsB + 4096);
    asm volatile("s_waitcnt vmcnt(0)" ::: "memory");
    __syncthreads();

    bf16x8 af[4], bfr[4];
#pragma unroll
    for (int m = 0; m < 4; ++m)
      af[m] = *(const bf16x8*)(As + (wm + m*16 + l15) * 32 + l4 * 8);
#pragma unroll
    for (int n = 0; n < 4; ++n)
      bfr[n] = *(const bf16x8*)(Bs + (wn + n*16 + l15) * 32 + l4 * 8);
#pragma unroll
    for (int m = 0; m < 4; ++m)
#pragma unroll
      for (int n = 0; n < 4; ++n)
        acc[m][n] = __builtin_amdgcn_mfma_f32_16x16x32_bf16(af[m], bfr[n], acc[m][n], 0, 0, 0);
    __syncthreads();
  }

  const int colbase = bn + wn;            // multiple of 64 -> wave-uniform region/head
  if (colbase < 2048) {                   // Q region (RoPE + scale)
    const int h = colbase >> 6;
#pragma unroll
    for (int m = 0; m < 4; ++m) {
#pragma unroll
      for (int r = 0; r < 4; ++r) {
        const int srow = bm + wm + m*16 + l4*4 + r;
        const int b = srow >> 11, s = srow & 2047;
        const float* cs = cosb + s * HD_;
        const float* sn = sinb + s * HD_;
        bf16_t* qp = Q + ((int64_t)(b * H_ + h) * S_ + s) * HD_;
#pragma unroll
        for (int n = 0; n < 4; ++n) {
          const int d = n*16 + l15;
          const float sgn = (n & 2) ? 1.f : -1.f;
          float o = (acc[m][n][r] * cs[d] + sgn * acc[m][n^2][r] * sn[d]) * QSCALE;
          qp[d] = (bf16_t)o;
        }
      }
    }
  } else if (colbase < 2560) {            // K region (RoPE)
    const int kvh = (colbase - 2048) >> 6;
#pragma unroll
    for (int m = 0; m < 4; ++m) {
#pragma unroll
      for (int r = 0; r < 4; ++r) {
        const int srow = bm + wm + m*16 + l4*4 + r;
        const int b = srow >> 11, s = srow & 2047;
        const float* cs = cosb + s * HD_;
        const float* sn = sinb + s * HD_;
        bf16_t* kp = Kr + ((int64_t)(b * KV_ + kvh) * S_ + s) * HD_;
#pragma unroll
        for (int n = 0; n < 4; ++n) {
          const int d = n*16 + l15;
          const float sgn = (n & 2) ? 1.f : -1.f;
          float o = acc[m][n][r] * cs[d] + sgn * acc[m][n^2][r] * sn[d];
          kp[d] = (bf16_t)o;
        }
      }
    }
  } else {                                // V region (row-major, coalesced)
    const int ccb = colbase - 2560;
#pragma unroll
    for (int m = 0; m < 4; ++m) {
#pragma unroll
      for (int r = 0; r < 4; ++r) {
        const int srow = bm + wm + m*16 + l4*4 + r;
        bf16_t* vp = Vbuf + (int64_t)srow * 512 + ccb;
#pragma unroll
        for (int n = 0; n < 4; ++n)
          vp[n*16 + l15] = (bf16_t)acc[m][n][r];
      }
    }
  }
}

// ---------------- flash attention: block-cooperative LDS-staged K/V ----------------
// grid (16 = b*8+kvh, 32 = qc). 512 thr = 8 waves: wave w -> head kvh*4+(w&3),
// q-rows qc*64 + (w>>2)*32. All waves share K/V tiles staged in LDS (double-buffered,
// XOR-swizzled via pre-swizzled global source; linear gload_lds dest).
#define SHIFT_ 8.0f
__global__ __launch_bounds__(512, 2) void attn5(const bf16_t* __restrict__ Q,
                                                const bf16_t* __restrict__ Kr,
                                                const bf16_t* __restrict__ Vt,
                                                bf16_t* __restrict__ AO) {
  const int bk = blockIdx.x;
  const int b = bk >> 3, kvh = bk & 7;
  const int qc = 31 - (int)blockIdx.y;    // longest blocks dispatched first
  const int tid = threadIdx.x;
  const int w = tid >> 6, lane = tid & 63;
  const int l31 = lane & 31, hi = lane >> 5;
  const int h = kvh * 4 + (w & 3);
  const int q0w = qc * 64 + (w >> 2) * 32;

  __shared__ __align__(16) bf16_t Ks[2][64 * 64];   // [buf][kv][d]   (swizzled 16B granules)
  __shared__ __align__(16) bf16_t Vs[2][64 * 64];   // [buf][d][kv]

  const bf16_t* Qb = Q  + ((int64_t)(b * H_ + h) * S_ + q0w) * HD_;
  const bf16_t* Kg = Kr + (int64_t)(b * KV_ + kvh) * S_ * HD_;
  const bf16_t* Vg = Vt + (int64_t)(b * KV_ + kvh) * HD_ * S_;   // [d][s]

  // staging map: wave w writes LDS rows 8w..8w+7 linearly (lane*16B).
  // source pre-swizzled: lane -> row rL = 8w + (lane>>3), granule (lane&7)^(rL&7)
  const int rL = (w << 3) + (lane >> 3);
  const int sgr = ((lane & 7) ^ (rL & 7)) << 3;     // element offset
  const bf16_t* Ksrc = Kg + rL * HD_ + sgr;
  const bf16_t* Vsrc = Vg + (int64_t)rL * S_ + sgr;
  char* KsDst = (char*)&Ks[0][0] + w * 1024;
  char* VsDst = (char*)&Vs[0][0] + w * 1024;

  bf16x8 qf[4];
#pragma unroll
  for (int ds = 0; ds < 4; ++ds)
    qf[ds] = *(const bf16x8*)(Qb + l31 * HD_ + ds * 16 + hi * 8);

  f32x16 accO0 = {}, accO1 = {};          // O^T partial: rows d 0-31/32-63, col q = l31
  float lhalf = 0.f;
  const int NT = qc + 1;                  // 64-kv tiles
  const int xorb = l31 & 7;

  const char* KsB = (const char*)&Ks[0][0];
  const char* VsB = (const char*)&Vs[0][0];

  // prologue: stage tile 0 into buf 0
  gload_lds16(Ksrc, KsDst);
  gload_lds16(Vsrc, VsDst);
  asm volatile("s_waitcnt vmcnt(0)" ::: "memory");
  __syncthreads();

  for (int t = 0; t < NT; ++t) {
    const int cur = t & 1;
    if (t + 1 < NT) {                     // stage next tile into other buffer
      gload_lds16(Ksrc + (t + 1) * 64 * HD_, KsDst + (cur ^ 1) * 8192);
      gload_lds16(Vsrc + (t + 1) * 64,      VsDst + (cur ^ 1) * 8192);
    }
#pragma unroll
    for (int sub = 0; sub < 2; ++sub) {
      const int kvbase = t * 64 + sub * 32;
      if (kvbase <= q0w) {                // not fully masked (wave-uniform)
        const bool diag = (kvbase == q0w);
        // ---- QK^T from LDS K ----
        const char* Kbase = KsB + cur * 8192 + (sub * 32 + l31) * 128;
        f32x16 sacc = {};
        __builtin_amdgcn_s_setprio(1);
#pragma unroll
        for (int ds = 0; ds < 4; ++ds) {
          bf16x8 kf = *(const bf16x8*)(Kbase + ((((ds << 1) + hi) ^ xorb) << 4));
          sacc = __builtin_amdgcn_mfma_f32_32x32x16_bf16(kf, qf[ds], sacc, 0, 0, 0);
        }
        __builtin_amdgcn_s_setprio(0);
        // ---- static-shift softmax + pack ----
        float p[16];
#pragma unroll
        for (int r = 0; r < 16; ++r) {
          float sc = sacc[r];
          if (diag) {
            int kvpos = (r & 3) + 8 * (r >> 2) + 4 * hi;
            if (kvpos > l31) sc = -1e30f;
          }
          p[r] = __builtin_amdgcn_exp2f(sc - SHIFT_);
        }
        float t0 = (p[0] + p[1]) + (p[2] + p[3]);
        float t1 = (p[4] + p[5]) + (p[6] + p[7]);
        float t2 = (p[8] + p[9]) + (p[10] + p[11]);
        float t3 = (p[12] + p[13]) + (p[14] + p[15]);
        lhalf += (t0 + t1) + (t2 + t3);
        u32 pk[8];
#pragma unroll
        for (int i = 0; i < 8; ++i) pk[i] = pkbf(p[2*i], p[2*i+1]);
        u32 a0 = pk[0], b0 = pk[2]; pl32swap(a0, b0);
        u32 a1 = pk[1], b1 = pk[3]; pl32swap(a1, b1);
        u32 a2 = pk[4], b2 = pk[6]; pl32swap(a2, b2);
        u32 a3 = pk[5], b3 = pk[7]; pl32swap(a3, b3);
        bf16x8 pf0 = __builtin_bit_cast(bf16x8, (u32x4){a0, a1, b0, b1});
        bf16x8 pf1 = __builtin_bit_cast(bf16x8, (u32x4){a2, a3, b2, b3});
        // ---- PV from LDS V^T ----
        const char* Vb0 = VsB + cur * 8192 + l31 * 128;
        const char* Vb1 = VsB + cur * 8192 + (32 + l31) * 128;
        const int c0 = (sub << 2) + hi;         // s2 = 0
        const int c1 = (sub << 2) + 2 + hi;     // s2 = 1
        bf16x8 v00 = *(const bf16x8*)(Vb0 + ((c0 ^ xorb) << 4));
        bf16x8 v01 = *(const bf16x8*)(Vb0 + ((c1 ^ xorb) << 4));
        bf16x8 v10 = *(const bf16x8*)(Vb1 + ((c0 ^ xorb) << 4));
        bf16x8 v11 = *(const bf16x8*)(Vb1 + ((c1 ^ xorb) << 4));
        __builtin_amdgcn_s_setprio(1);
        accO0 = __builtin_amdgcn_mfma_f32_32x32x16_bf16(v00, pf0, accO0, 0, 0, 0);
        accO1 = __builtin_amdgcn_mfma_f32_32x32x16_bf16(v10, pf0, accO1, 0, 0, 0);
        accO0 = __builtin_amdgcn_mfma_f32_32x32x16_bf16(v01, pf1, accO0, 0, 0, 0);
        accO1 = __builtin_amdgcn_mfma_f32_32x32x16_bf16(v11, pf1, accO1, 0, 0, 0);
        __builtin_amdgcn_s_setprio(0);
      }
    }
    asm volatile("s_waitcnt vmcnt(0)" ::: "memory");
    __syncthreads();
  }

  float lrun = lhalf + __shfl_xor(lhalf, 32);
  const float rl = 1.f / lrun;
  const int64_t row = (int64_t)(b * S_ + q0w + l31);
#pragma unroll
  for (int dt = 0; dt < 2; ++dt) {
#pragma unroll
    for (int g = 0; g < 4; ++g) {
      bf16x4 ov;
#pragma unroll
      for (int j = 0; j < 4; ++j) {
        float val = (dt ? accO1[4*g + j] : accO0[4*g + j]) * rl;
        ov[j] = (bf16_t)val;
      }
      const int d0 = dt * 32 + g * 8 + hi * 4;
      *(bf16x4*)(AO + row * D_ + h * HD_ + d0) = ov;
    }
  }
}

// ---------------- launcher ----------------
extern "C" void kernel_launch(void* const* d_in, const int* in_sizes, int n_in,
                              void* d_out, int out_size, void* d_ws, size_t ws_size,
                              hipStream_t stream) {
  const float* x    = (const float*)d_in[0];
  const float* cosb = (const float*)d_in[1];
  const float* sinb = (const float*)d_in[2];
  const float* Wq   = (const float*)d_in[3];
  const float* Wk   = (const float*)d_in[4];
  const float* Wv   = (const float*)d_in[5];
  const float* Wo   = (const float*)d_in[6];
  float* out = (float*)d_out;

  bf16_t* ws = (bf16_t*)d_ws;
  size_t o = 0;
  bf16_t* xb    = ws + o; o += (size_t)4096 * 2048;
  bf16_t* Wqkvt = ws + o; o += (size_t)3072 * 2048;
  bf16_t* Wot   = ws + o; o += (size_t)2048 * 2048;
  bf16_t* Qr    = ws + o; o += (size_t)B_ * H_ * S_ * HD_;
  bf16_t* Krb   = ws + o; o += (size_t)B_ * KV_ * S_ * HD_;
  bf16_t* Vtb   = ws + o; o += (size_t)B_ * KV_ * S_ * HD_;
  bf16_t* Vbuf  = ws + o; o += (size_t)B_ * S_ * 512;
  bf16_t* AO    = ws + o; o += (size_t)4096 * 2048;

  cvt_f32_bf16<<<(8388608/4 + 255)/256, 256, 0, stream>>>(x, xb, 8388608/4);
  transpose_cvt<<<dim3(2048/32, 2048/32), dim3(32, 8), 0, stream>>>(Wq, Wqkvt, 2048, 0);
  transpose_cvt<<<dim3(512/32, 2048/32),  dim3(32, 8), 0, stream>>>(Wk, Wqkvt, 512, 2048);
  transpose_cvt<<<dim3(512/32, 2048/32),  dim3(32, 8), 0, stream>>>(Wv, Wqkvt, 512, 2560);
  transpose_cvt<<<dim3(2048/32, 2048/32), dim3(32, 8), 0, stream>>>(Wo, Wot, 2048, 0);
  // fused QKV projection + RoPE + scatter (V row-major)
  gemm_qkv<<<dim3(3072/128, 4096/128), 256, 0, stream>>>(xb, Wqkvt, cosb, sinb, Qr, Krb, Vbuf);
  // V transpose to [b][d][s]
  v_transpose<<<dim3(16, 64, 2), dim3(32, 8), 0, stream>>>(Vbuf, Vtb);
  // block-cooperative LDS-staged attention
  attn5<<<dim3(16, 32), 512, 0, stream>>>(Qr, Krb, Vtb, AO);
  // output projection -> f32
  gemm_bt<float><<<dim3(2048/128, 4096/128), 256, 0, stream>>>(AO, Wot, out, 4096, 2048, 2048);
}

// Round 8
// 190.444 us; speedup vs baseline: 1.6036x; 1.2445x over previous
//
#include <hip/hip_runtime.h>
#include <hip/hip_bf16.h>
#include <stdint.h>

#define B_ 2
#define S_ 2048
#define D_ 2048
#define H_ 32
#define KV_ 8
#define HD_ 64
#define NQKV 3072   // D + 2*KV*HD

typedef __bf16 bf16_t;
typedef __bf16 bf16x8 __attribute__((ext_vector_type(8)));
typedef __bf16 bf16x4 __attribute__((ext_vector_type(4)));
typedef float  f32x4  __attribute__((ext_vector_type(4)));
typedef float  f32x16 __attribute__((ext_vector_type(16)));
typedef unsigned int u32;
typedef u32 u32x4 __attribute__((ext_vector_type(4)));

typedef const __attribute__((address_space(1))) uint32_t* gp1_t;
typedef __attribute__((address_space(3))) uint32_t* lp3_t;

// async global->LDS, 16B per lane. LDS dest is wave-uniform base + lane*16.
__device__ inline void gload_lds16(const void* g, void* l) {
  __builtin_amdgcn_global_load_lds((gp1_t)(uintptr_t)g, (lp3_t)(uint32_t)(uintptr_t)l,
                                   16, 0, 0);
}

__device__ inline u32 pkbf(float a, float b) {
  union { bf16_t h[2]; u32 u; } v;
  v.h[0] = (bf16_t)a; v.h[1] = (bf16_t)b;
  return v.u;
}

// v_permlane32_swap_b32: a = [a_lo, b_lo], b = [a_hi, b_hi]
__device__ inline void pl32swap(u32 &a, u32 &b) {
  asm("v_permlane32_swap_b32 %0, %1" : "+v"(a), "+v"(b));
}

// ---------------- converts ----------------
__global__ void cvt_f32_bf16(const float* __restrict__ in, bf16_t* __restrict__ out, int n4) {
  int i = blockIdx.x * blockDim.x + threadIdx.x;
  if (i < n4) {
    float4 v = ((const float4*)in)[i];
    bf16x4 o;
    o[0] = (bf16_t)v.x; o[1] = (bf16_t)v.y; o[2] = (bf16_t)v.z; o[3] = (bf16_t)v.w;
    ((bf16x4*)out)[i] = o;
  }
}

// transpose + cast: out[row_off + c][r] = in[r][c]
__global__ void transpose_cvt(const float* __restrict__ in, bf16_t* __restrict__ out,
                              int C, int row_off) {
  __shared__ float t[32][33];
  int tx = threadIdx.x, ty = threadIdx.y;       // (32,8)
  int c0 = blockIdx.x * 32, r0 = blockIdx.y * 32;
#pragma unroll
  for (int j = 0; j < 4; ++j)
    t[ty + j*8][tx] = in[(int64_t)(r0 + ty + j*8) * C + c0 + tx];
  __syncthreads();
#pragma unroll
  for (int j = 0; j < 4; ++j)
    out[(int64_t)(row_off + c0 + ty + j*8) * 2048 + r0 + tx] = (bf16_t)t[tx][ty + j*8];
}

// Vbuf[b][s][cc] -> Vt[b][cc][s]  (LDS-tiled transpose, coalesced both sides)
__global__ void v_transpose(const bf16_t* __restrict__ Vbuf, bf16_t* __restrict__ Vt) {
  __shared__ bf16_t t[32][34];
  const int tx = threadIdx.x, ty = threadIdx.y;   // (32,8)
  const int c0 = blockIdx.x * 32;                 // cc within 512
  const int s0 = blockIdx.y * 32;
  const int b  = blockIdx.z;
#pragma unroll
  for (int j = 0; j < 4; ++j)
    t[ty + j*8][tx] = Vbuf[(int64_t)(b * S_ + s0 + ty + j*8) * 512 + c0 + tx];
  __syncthreads();
#pragma unroll
  for (int j = 0; j < 4; ++j)
    Vt[(int64_t)(b * 512 + c0 + ty + j*8) * S_ + s0 + tx] = t[tx][ty + j*8];
}

// ---------------- 256-row deep-pipelined GEMM ----------------
// BM=256, BK=64, 8 waves (512 thr). Wave (wr,wc): rows wr*128+[0,128), cols wc*(BN/4)+[0,BN/4).
// LDS double-buffered; tile t+1 staged (granule-XOR swizzled via pre-swizzled global src)
// during phases 0-1 of tile t's compute; one vmcnt-drain + barrier per K-tile.
// EPI=0: plain float C. EPI=1: fused RoPE/scatter epilogue (QKV).
#define QSCALE 0.18033688011112042f
template <int BN, int EPI>
__global__ __launch_bounds__(512, 2) void gemm256(const bf16_t* __restrict__ A,
                                                  const bf16_t* __restrict__ Bt,
                                                  const float* __restrict__ cosb,
                                                  const float* __restrict__ sinb,
                                                  bf16_t* __restrict__ Q,
                                                  bf16_t* __restrict__ Kr,
                                                  bf16_t* __restrict__ Vbuf,
                                                  float* __restrict__ Cout,
                                                  int N, int K) {
  constexpr int NB = BN / 64;          // B stage loads per tile
  constexpr int LT = 4 + NB;           // total stage loads per tile
  constexpr int WCOLS = BN / 4;        // per-wave cols
  constexpr int NF = WCOLS / 16;       // per-wave n fragments (4 or 2)
  constexpr int NHALF = NF / 2;        // n frags per phase (2 or 1)

  __shared__ bf16_t As[2][256 * 64];
  __shared__ bf16_t Bs[2][BN * 64];

  const int tid = threadIdx.x;
  const int w = tid >> 6, lane = tid & 63;
  const int l15 = lane & 15, l4 = lane >> 4;
  const int wr = w >> 2, wc = w & 3;
  const int bm = blockIdx.y * 256, bn = blockIdx.x * BN;

  // staging source (pre-swizzled): row = L*64 + w*8 + lane>>3; granule = (lane&7)^(row&7)
  const int rw = w * 8 + (lane >> 3);
  const int srcg = ((lane & 7) ^ ((lane >> 3) & 7)) << 3;   // element offset
  const bf16_t* PA[4];
  const bf16_t* PB[NB];
#pragma unroll
  for (int L = 0; L < 4; ++L)
    PA[L] = A + (int64_t)(bm + L * 64 + rw) * K + srcg;
#pragma unroll
  for (int L = 0; L < NB; ++L)
    PB[L] = Bt + (int64_t)(bn + L * 64 + rw) * K + srcg;

  const int NK = K >> 6;
  const int xr = l15 & 7;
  const int g0 = (l4 ^ xr) << 3;          // kk=0 slot, element offset
  const int g1 = ((4 + l4) ^ xr) << 3;    // kk=1 slot

  f32x4 acc[8][NF] = {};

  // prologue: stage tile 0 into buf 0
#pragma unroll
  for (int s = 0; s < LT; ++s) {
    if (s < 4) gload_lds16(PA[s], &As[0][s * 4096 + w * 512]);
    else       gload_lds16(PB[s - 4], &Bs[0][(s - 4) * 4096 + w * 512]);
  }
  asm volatile("s_waitcnt vmcnt(0)" ::: "memory");
  __syncthreads();

  for (int t = 0; t < NK; ++t) {
    const int p = t & 1;
    const bool more = (t + 1) < NK;
    const int toff = (t + 1) << 6;
    const bf16_t* Ab = &As[p][0];
    const bf16_t* Bb = &Bs[p][0];
#pragma unroll
    for (int q = 0; q < 4; ++q) {
      // issue next-tile stages in phases 0-1 (latency hidden under this tile's MFMA)
      if (q < 2 && more) {
        const int s0 = q * (LT / 2), s1 = s0 + LT / 2;
#pragma unroll
        for (int s = s0; s < s1; ++s) {
          if (s < 4) gload_lds16(PA[s] + toff, &As[p ^ 1][s * 4096 + w * 512]);
          else       gload_lds16(PB[s - 4] + toff, &Bs[p ^ 1][(s - 4) * 4096 + w * 512]);
        }
      }
      const int mh = q >> 1, nh = q & 1;
      bf16x8 af[4][2], bfv[NHALF][2];
#pragma unroll
      for (int mm = 0; mm < 4; ++mm) {
        const int ra = wr * 128 + (mh * 4 + mm) * 16 + l15;
        af[mm][0] = *(const bf16x8*)(Ab + ra * 64 + g0);
        af[mm][1] = *(const bf16x8*)(Ab + ra * 64 + g1);
      }
#pragma unroll
      for (int nn = 0; nn < NHALF; ++nn) {
        const int rb = wc * WCOLS + (nh * NHALF + nn) * 16 + l15;
        bfv[nn][0] = *(const bf16x8*)(Bb + rb * 64 + g0);
        bfv[nn][1] = *(const bf16x8*)(Bb + rb * 64 + g1);
      }
      __builtin_amdgcn_s_setprio(1);
#pragma unroll
      for (int mm = 0; mm < 4; ++mm)
#pragma unroll
        for (int nn = 0; nn < NHALF; ++nn) {
          acc[mh*4+mm][nh*NHALF+nn] = __builtin_amdgcn_mfma_f32_16x16x32_bf16(
              af[mm][0], bfv[nn][0], acc[mh*4+mm][nh*NHALF+nn], 0, 0, 0);
          acc[mh*4+mm][nh*NHALF+nn] = __builtin_amdgcn_mfma_f32_16x16x32_bf16(
              af[mm][1], bfv[nn][1], acc[mh*4+mm][nh*NHALF+nn], 0, 0, 0);
        }
      __builtin_amdgcn_s_setprio(0);
    }
    if (more) {
      asm volatile("s_waitcnt vmcnt(0)" ::: "memory");
      __syncthreads();
    }
  }

  if constexpr (EPI == 0) {             // plain float C
#pragma unroll
    for (int m = 0; m < 8; ++m) {
      const int row = bm + wr * 128 + m * 16 + l4 * 4;
#pragma unroll
      for (int n = 0; n < NF; ++n) {
        const int col = bn + wc * WCOLS + n * 16 + l15;
#pragma unroll
        for (int r = 0; r < 4; ++r)
          Cout[(int64_t)(row + r) * N + col] = acc[m][n][r];
      }
    }
  } else {                              // fused RoPE / scatter epilogue (BN=256)
    const int colbase = bn + wc * 64;   // wave-uniform, 64-aligned -> one head
    if (colbase < 2048) {               // Q region (RoPE + scale)
      const int h = colbase >> 6;
#pragma unroll
      for (int m = 0; m < 8; ++m) {
#pragma unroll
        for (int r = 0; r < 4; ++r) {
          const int srow = bm + wr * 128 + m * 16 + l4 * 4 + r;
          const int b = srow >> 11, s = srow & 2047;
          const float* cs = cosb + s * HD_;
          const float* sn = sinb + s * HD_;
          bf16_t* qp = Q + ((int64_t)(b * H_ + h) * S_ + s) * HD_;
#pragma unroll
          for (int n = 0; n < 4; ++n) {
            const int d = n * 16 + l15;
            const float sgn = (n & 2) ? 1.f : -1.f;
            float o = (acc[m][n][r] * cs[d] + sgn * acc[m][n ^ 2][r] * sn[d]) * QSCALE;
            qp[d] = (bf16_t)o;
          }
        }
      }
    } else if (colbase < 2560) {        // K region (RoPE)
      const int kvh = (colbase - 2048) >> 6;
#pragma unroll
      for (int m = 0; m < 8; ++m) {
#pragma unroll
        for (int r = 0; r < 4; ++r) {
          const int srow = bm + wr * 128 + m * 16 + l4 * 4 + r;
          const int b = srow >> 11, s = srow & 2047;
          const float* cs = cosb + s * HD_;
          const float* sn = sinb + s * HD_;
          bf16_t* kp = Kr + ((int64_t)(b * KV_ + kvh) * S_ + s) * HD_;
#pragma unroll
          for (int n = 0; n < 4; ++n) {
            const int d = n * 16 + l15;
            const float sgn = (n & 2) ? 1.f : -1.f;
            float o = acc[m][n][r] * cs[d] + sgn * acc[m][n ^ 2][r] * sn[d];
            kp[d] = (bf16_t)o;
          }
        }
      }
    } else {                            // V region (row-major, coalesced)
      const int ccb = colbase - 2560;
#pragma unroll
      for (int m = 0; m < 8; ++m) {
#pragma unroll
        for (int r = 0; r < 4; ++r) {
          const int srow = bm + wr * 128 + m * 16 + l4 * 4 + r;
          bf16_t* vp = Vbuf + (int64_t)srow * 512 + ccb;
#pragma unroll
          for (int n = 0; n < 4; ++n)
            vp[n * 16 + l15] = (bf16_t)acc[m][n][r];
        }
      }
    }
  }
}

// ---------------- flash attention: block-cooperative LDS-staged K/V ----------------
#define SHIFT_ 8.0f
__global__ __launch_bounds__(512, 2) void attn5(const bf16_t* __restrict__ Q,
                                                const bf16_t* __restrict__ Kr,
                                                const bf16_t* __restrict__ Vt,
                                                bf16_t* __restrict__ AO) {
  const int bk = blockIdx.x;
  const int b = bk >> 3, kvh = bk & 7;
  const int qc = 31 - (int)blockIdx.y;    // longest blocks dispatched first
  const int tid = threadIdx.x;
  const int w = tid >> 6, lane = tid & 63;
  const int l31 = lane & 31, hi = lane >> 5;
  const int h = kvh * 4 + (w & 3);
  const int q0w = qc * 64 + (w >> 2) * 32;

  __shared__ __align__(16) bf16_t Ks[2][64 * 64];   // [buf][kv][d]   (swizzled 16B granules)
  __shared__ __align__(16) bf16_t Vs[2][64 * 64];   // [buf][d][kv]

  const bf16_t* Qb = Q  + ((int64_t)(b * H_ + h) * S_ + q0w) * HD_;
  const bf16_t* Kg = Kr + (int64_t)(b * KV_ + kvh) * S_ * HD_;
  const bf16_t* Vg = Vt + (int64_t)(b * KV_ + kvh) * HD_ * S_;   // [d][s]

  const int rL = (w << 3) + (lane >> 3);
  const int sgr = ((lane & 7) ^ (rL & 7)) << 3;     // element offset
  const bf16_t* Ksrc = Kg + rL * HD_ + sgr;
  const bf16_t* Vsrc = Vg + (int64_t)rL * S_ + sgr;
  char* KsDst = (char*)&Ks[0][0] + w * 1024;
  char* VsDst = (char*)&Vs[0][0] + w * 1024;

  bf16x8 qf[4];
#pragma unroll
  for (int ds = 0; ds < 4; ++ds)
    qf[ds] = *(const bf16x8*)(Qb + l31 * HD_ + ds * 16 + hi * 8);

  f32x16 accO0 = {}, accO1 = {};          // O^T partial: rows d 0-31/32-63, col q = l31
  float lhalf = 0.f;
  const int NT = qc + 1;                  // 64-kv tiles
  const int xorb = l31 & 7;

  const char* KsB = (const char*)&Ks[0][0];
  const char* VsB = (const char*)&Vs[0][0];

  gload_lds16(Ksrc, KsDst);
  gload_lds16(Vsrc, VsDst);
  asm volatile("s_waitcnt vmcnt(0)" ::: "memory");
  __syncthreads();

  for (int t = 0; t < NT; ++t) {
    const int cur = t & 1;
    if (t + 1 < NT) {
      gload_lds16(Ksrc + (t + 1) * 64 * HD_, KsDst + (cur ^ 1) * 8192);
      gload_lds16(Vsrc + (t + 1) * 64,      VsDst + (cur ^ 1) * 8192);
    }
#pragma unroll
    for (int sub = 0; sub < 2; ++sub) {
      const int kvbase = t * 64 + sub * 32;
      if (kvbase <= q0w) {
        const bool diag = (kvbase == q0w);
        const char* Kbase = KsB + cur * 8192 + (sub * 32 + l31) * 128;
        f32x16 sacc = {};
        __builtin_amdgcn_s_setprio(1);
#pragma unroll
        for (int ds = 0; ds < 4; ++ds) {
          bf16x8 kf = *(const bf16x8*)(Kbase + ((((ds << 1) + hi) ^ xorb) << 4));
          sacc = __builtin_amdgcn_mfma_f32_32x32x16_bf16(kf, qf[ds], sacc, 0, 0, 0);
        }
        __builtin_amdgcn_s_setprio(0);
        float p[16];
#pragma unroll
        for (int r = 0; r < 16; ++r) {
          float sc = sacc[r];
          if (diag) {
            int kvpos = (r & 3) + 8 * (r >> 2) + 4 * hi;
            if (kvpos > l31) sc = -1e30f;
          }
          p[r] = __builtin_amdgcn_exp2f(sc - SHIFT_);
        }
        float t0 = (p[0] + p[1]) + (p[2] + p[3]);
        float t1 = (p[4] + p[5]) + (p[6] + p[7]);
        float t2 = (p[8] + p[9]) + (p[10] + p[11]);
        float t3 = (p[12] + p[13]) + (p[14] + p[15]);
        lhalf += (t0 + t1) + (t2 + t3);
        u32 pk[8];
#pragma unroll
        for (int i = 0; i < 8; ++i) pk[i] = pkbf(p[2*i], p[2*i+1]);
        u32 a0 = pk[0], b0 = pk[2]; pl32swap(a0, b0);
        u32 a1 = pk[1], b1 = pk[3]; pl32swap(a1, b1);
        u32 a2 = pk[4], b2 = pk[6]; pl32swap(a2, b2);
        u32 a3 = pk[5], b3 = pk[7]; pl32swap(a3, b3);
        bf16x8 pf0 = __builtin_bit_cast(bf16x8, (u32x4){a0, a1, b0, b1});
        bf16x8 pf1 = __builtin_bit_cast(bf16x8, (u32x4){a2, a3, b2, b3});
        const char* Vb0 = VsB + cur * 8192 + l31 * 128;
        const char* Vb1 = VsB + cur * 8192 + (32 + l31) * 128;
        const int c0 = (sub << 2) + hi;
        const int c1 = (sub << 2) + 2 + hi;
        bf16x8 v00 = *(const bf16x8*)(Vb0 + ((c0 ^ xorb) << 4));
        bf16x8 v01 = *(const bf16x8*)(Vb0 + ((c1 ^ xorb) << 4));
        bf16x8 v10 = *(const bf16x8*)(Vb1 + ((c0 ^ xorb) << 4));
        bf16x8 v11 = *(const bf16x8*)(Vb1 + ((c1 ^ xorb) << 4));
        __builtin_amdgcn_s_setprio(1);
        accO0 = __builtin_amdgcn_mfma_f32_32x32x16_bf16(v00, pf0, accO0, 0, 0, 0);
        accO1 = __builtin_amdgcn_mfma_f32_32x32x16_bf16(v10, pf0, accO1, 0, 0, 0);
        accO0 = __builtin_amdgcn_mfma_f32_32x32x16_bf16(v01, pf1, accO0, 0, 0, 0);
        accO1 = __builtin_amdgcn_mfma_f32_32x32x16_bf16(v11, pf1, accO1, 0, 0, 0);
        __builtin_amdgcn_s_setprio(0);
      }
    }
    asm volatile("s_waitcnt vmcnt(0)" ::: "memory");
    __syncthreads();
  }

  float lrun = lhalf + __shfl_xor(lhalf, 32);
  const float rl = 1.f / lrun;
  const int64_t row = (int64_t)(b * S_ + q0w + l31);
#pragma unroll
  for (int dt = 0; dt < 2; ++dt) {
#pragma unroll
    for (int g = 0; g < 4; ++g) {
      bf16x4 ov;
#pragma unroll
      for (int j = 0; j < 4; ++j) {
        float val = (dt ? accO1[4*g + j] : accO0[4*g + j]) * rl;
        ov[j] = (bf16_t)val;
      }
      const int d0 = dt * 32 + g * 8 + hi * 4;
      *(bf16x4*)(AO + row * D_ + h * HD_ + d0) = ov;
    }
  }
}

// ---------------- launcher ----------------
extern "C" void kernel_launch(void* const* d_in, const int* in_sizes, int n_in,
                              void* d_out, int out_size, void* d_ws, size_t ws_size,
                              hipStream_t stream) {
  const float* x    = (const float*)d_in[0];
  const float* cosb = (const float*)d_in[1];
  const float* sinb = (const float*)d_in[2];
  const float* Wq   = (const float*)d_in[3];
  const float* Wk   = (const float*)d_in[4];
  const float* Wv   = (const float*)d_in[5];
  const float* Wo   = (const float*)d_in[6];
  float* out = (float*)d_out;

  bf16_t* ws = (bf16_t*)d_ws;
  size_t o = 0;
  bf16_t* xb    = ws + o; o += (size_t)4096 * 2048;
  bf16_t* Wqkvt = ws + o; o += (size_t)3072 * 2048;
  bf16_t* Wot   = ws + o; o += (size_t)2048 * 2048;
  bf16_t* Qr    = ws + o; o += (size_t)B_ * H_ * S_ * HD_;
  bf16_t* Krb   = ws + o; o += (size_t)B_ * KV_ * S_ * HD_;
  bf16_t* Vtb   = ws + o; o += (size_t)B_ * KV_ * S_ * HD_;
  bf16_t* Vbuf  = ws + o; o += (size_t)B_ * S_ * 512;
  bf16_t* AO    = ws + o; o += (size_t)4096 * 2048;

  cvt_f32_bf16<<<(8388608/4 + 255)/256, 256, 0, stream>>>(x, xb, 8388608/4);
  transpose_cvt<<<dim3(2048/32, 2048/32), dim3(32, 8), 0, stream>>>(Wq, Wqkvt, 2048, 0);
  transpose_cvt<<<dim3(512/32, 2048/32),  dim3(32, 8), 0, stream>>>(Wk, Wqkvt, 512, 2048);
  transpose_cvt<<<dim3(512/32, 2048/32),  dim3(32, 8), 0, stream>>>(Wv, Wqkvt, 512, 2560);
  transpose_cvt<<<dim3(2048/32, 2048/32), dim3(32, 8), 0, stream>>>(Wo, Wot, 2048, 0);
  // fused QKV projection + RoPE + scatter (256x256 deep-pipelined)
  gemm256<256, 1><<<dim3(3072/256, 4096/256), 512, 0, stream>>>(
      xb, Wqkvt, cosb, sinb, Qr, Krb, Vbuf, nullptr, 3072, 2048);
  // V transpose to [b][d][s]
  v_transpose<<<dim3(16, 64, 2), dim3(32, 8), 0, stream>>>(Vbuf, Vtb);
  // block-cooperative LDS-staged attention
  attn5<<<dim3(16, 32), 512, 0, stream>>>(Qr, Krb, Vtb, AO);
  // output projection -> f32 (256x128 deep-pipelined, 256 blocks = 1/CU)
  gemm256<128, 0><<<dim3(2048/128, 4096/256), 512, 0, stream>>>(
      AO, Wot, nullptr, nullptr, nullptr, nullptr, nullptr, out, 2048, 2048);
}

// Round 9
// 187.172 us; speedup vs baseline: 1.6316x; 1.0175x over previous
//
#include <hip/hip_runtime.h>
#include <hip/hip_bf16.h>
#include <stdint.h>

#define B_ 2
#define S_ 2048
#define D_ 2048
#define H_ 32
#define KV_ 8
#define HD_ 64
#define NQKV 3072   // D + 2*KV*HD

typedef __bf16 bf16_t;
typedef __bf16 bf16x8 __attribute__((ext_vector_type(8)));
typedef __bf16 bf16x4 __attribute__((ext_vector_type(4)));
typedef float  f32x4  __attribute__((ext_vector_type(4)));
typedef float  f32x16 __attribute__((ext_vector_type(16)));
typedef unsigned int u32;
typedef u32 u32x4 __attribute__((ext_vector_type(4)));

typedef const __attribute__((address_space(1))) uint32_t* gp1_t;
typedef __attribute__((address_space(3))) uint32_t* lp3_t;

// async global->LDS, 16B per lane. LDS dest is wave-uniform base + lane*16.
__device__ inline void gload_lds16(const void* g, void* l) {
  __builtin_amdgcn_global_load_lds((gp1_t)(uintptr_t)g, (lp3_t)(uint32_t)(uintptr_t)l,
                                   16, 0, 0);
}

__device__ inline u32 pkbf(float a, float b) {
  union { bf16_t h[2]; u32 u; } v;
  v.h[0] = (bf16_t)a; v.h[1] = (bf16_t)b;
  return v.u;
}

// v_permlane32_swap_b32: a = [a_lo, b_lo], b = [a_hi, b_hi]
__device__ inline void pl32swap(u32 &a, u32 &b) {
  asm("v_permlane32_swap_b32 %0, %1" : "+v"(a), "+v"(b));
}

// ---------------- converts ----------------
__global__ void cvt_f32_bf16(const float* __restrict__ in, bf16_t* __restrict__ out, int n4) {
  int i = blockIdx.x * blockDim.x + threadIdx.x;
  if (i < n4) {
    float4 v = ((const float4*)in)[i];
    bf16x4 o;
    o[0] = (bf16_t)v.x; o[1] = (bf16_t)v.y; o[2] = (bf16_t)v.z; o[3] = (bf16_t)v.w;
    ((bf16x4*)out)[i] = o;
  }
}

// transpose + cast: out[row_off + c][r] = in[r][c]
__global__ void transpose_cvt(const float* __restrict__ in, bf16_t* __restrict__ out,
                              int C, int row_off) {
  __shared__ float t[32][33];
  int tx = threadIdx.x, ty = threadIdx.y;       // (32,8)
  int c0 = blockIdx.x * 32, r0 = blockIdx.y * 32;
#pragma unroll
  for (int j = 0; j < 4; ++j)
    t[ty + j*8][tx] = in[(int64_t)(r0 + ty + j*8) * C + c0 + tx];
  __syncthreads();
#pragma unroll
  for (int j = 0; j < 4; ++j)
    out[(int64_t)(row_off + c0 + ty + j*8) * 2048 + r0 + tx] = (bf16_t)t[tx][ty + j*8];
}

// Vbuf[b][s][cc] -> Vt[b][cc][s]  (LDS-tiled transpose, coalesced both sides)
__global__ void v_transpose(const bf16_t* __restrict__ Vbuf, bf16_t* __restrict__ Vt) {
  __shared__ bf16_t t[32][34];
  const int tx = threadIdx.x, ty = threadIdx.y;   // (32,8)
  const int c0 = blockIdx.x * 32;                 // cc within 512
  const int s0 = blockIdx.y * 32;
  const int b  = blockIdx.z;
#pragma unroll
  for (int j = 0; j < 4; ++j)
    t[ty + j*8][tx] = Vbuf[(int64_t)(b * S_ + s0 + ty + j*8) * 512 + c0 + tx];
  __syncthreads();
#pragma unroll
  for (int j = 0; j < 4; ++j)
    Vt[(int64_t)(b * 512 + c0 + ty + j*8) * S_ + s0 + tx] = t[tx][ty + j*8];
}

// ---------------- 256-row deep-pipelined GEMM (dedup'd LDS reads) ----------------
// BM=256, BK=64, 8 waves. Per K-tile per wave: 8 B-frag reads (hoisted once) +
// 16 A-frag reads (once per mh half) + 64 MFMA. Stage t+1 issued inside the two
// mh halves; one vmcnt(0)+barrier per K-tile.
#define QSCALE 0.18033688011112042f
template <int BN, int EPI>
__global__ __launch_bounds__(512, 2) void gemm256(const bf16_t* __restrict__ A,
                                                  const bf16_t* __restrict__ Bt,
                                                  const float* __restrict__ cosb,
                                                  const float* __restrict__ sinb,
                                                  bf16_t* __restrict__ Q,
                                                  bf16_t* __restrict__ Kr,
                                                  bf16_t* __restrict__ Vbuf,
                                                  float* __restrict__ Cout,
                                                  int N, int K) {
  constexpr int NB = BN / 64;          // B stage loads per tile
  constexpr int LT = 4 + NB;           // total stage loads per tile
  constexpr int WCOLS = BN / 4;        // per-wave cols
  constexpr int NF = WCOLS / 16;       // per-wave n fragments (4 or 2)

  __shared__ bf16_t As[2][256 * 64];
  __shared__ bf16_t Bs[2][BN * 64];

  const int tid = threadIdx.x;
  const int w = tid >> 6, lane = tid & 63;
  const int l15 = lane & 15, l4 = lane >> 4;
  const int wr = w >> 2, wc = w & 3;
  const int bm = blockIdx.y * 256, bn = blockIdx.x * BN;

  // staging source (pre-swizzled): row = L*64 + w*8 + lane>>3; granule = (lane&7)^(row&7)
  const int rw = w * 8 + (lane >> 3);
  const int srcg = ((lane & 7) ^ ((lane >> 3) & 7)) << 3;   // element offset
  const bf16_t* PA[4];
  const bf16_t* PB[NB];
#pragma unroll
  for (int L = 0; L < 4; ++L)
    PA[L] = A + (int64_t)(bm + L * 64 + rw) * K + srcg;
#pragma unroll
  for (int L = 0; L < NB; ++L)
    PB[L] = Bt + (int64_t)(bn + L * 64 + rw) * K + srcg;

  const int NK = K >> 6;
  const int xr = l15 & 7;
  const int g0 = (l4 ^ xr) << 3;          // kk=0 slot, element offset
  const int g1 = ((4 + l4) ^ xr) << 3;    // kk=1 slot

  f32x4 acc[8][NF] = {};

  // prologue: stage tile 0 into buf 0
#pragma unroll
  for (int s = 0; s < LT; ++s) {
    if (s < 4) gload_lds16(PA[s], &As[0][s * 4096 + w * 512]);
    else       gload_lds16(PB[s - 4], &Bs[0][(s - 4) * 4096 + w * 512]);
  }
  asm volatile("s_waitcnt vmcnt(0)" ::: "memory");
  __syncthreads();

  for (int t = 0; t < NK; ++t) {
    const int p = t & 1;
    const bool more = (t + 1) < NK;
    const int toff = (t + 1) << 6;
    const bf16_t* Ab = &As[p][0];
    const bf16_t* Bb = &Bs[p][0];

    // hoist ALL B fragments for this tile (8 or 4 ds_read_b128)
    bf16x8 ball[NF][2];
#pragma unroll
    for (int nn = 0; nn < NF; ++nn) {
      const int rb = wc * WCOLS + nn * 16 + l15;
      ball[nn][0] = *(const bf16x8*)(Bb + rb * 64 + g0);
      ball[nn][1] = *(const bf16x8*)(Bb + rb * 64 + g1);
    }

#pragma unroll
    for (int mh = 0; mh < 2; ++mh) {
      // issue next-tile stages (half per mh) — latency hidden under MFMA
      if (more) {
        const int s0 = mh * (LT / 2), s1 = s0 + LT / 2;
#pragma unroll
        for (int s = s0; s < s1; ++s) {
          if (s < 4) gload_lds16(PA[s] + toff, &As[p ^ 1][s * 4096 + w * 512]);
          else       gload_lds16(PB[s - 4] + toff, &Bs[p ^ 1][(s - 4) * 4096 + w * 512]);
        }
      }
      bf16x8 af[4][2];
#pragma unroll
      for (int mm = 0; mm < 4; ++mm) {
        const int ra = wr * 128 + (mh * 4 + mm) * 16 + l15;
        af[mm][0] = *(const bf16x8*)(Ab + ra * 64 + g0);
        af[mm][1] = *(const bf16x8*)(Ab + ra * 64 + g1);
      }
      __builtin_amdgcn_s_setprio(1);
#pragma unroll
      for (int mm = 0; mm < 4; ++mm)
#pragma unroll
        for (int nn = 0; nn < NF; ++nn) {
          acc[mh*4+mm][nn] = __builtin_amdgcn_mfma_f32_16x16x32_bf16(
              af[mm][0], ball[nn][0], acc[mh*4+mm][nn], 0, 0, 0);
          acc[mh*4+mm][nn] = __builtin_amdgcn_mfma_f32_16x16x32_bf16(
              af[mm][1], ball[nn][1], acc[mh*4+mm][nn], 0, 0, 0);
        }
      __builtin_amdgcn_s_setprio(0);
    }
    if (more) {
      asm volatile("s_waitcnt vmcnt(0)" ::: "memory");
      __syncthreads();
    }
  }

  if constexpr (EPI == 0) {             // plain float C
#pragma unroll
    for (int m = 0; m < 8; ++m) {
      const int row = bm + wr * 128 + m * 16 + l4 * 4;
#pragma unroll
      for (int n = 0; n < NF; ++n) {
        const int col = bn + wc * WCOLS + n * 16 + l15;
#pragma unroll
        for (int r = 0; r < 4; ++r)
          Cout[(int64_t)(row + r) * N + col] = acc[m][n][r];
      }
    }
  } else {                              // fused RoPE / scatter epilogue (BN=256)
    const int colbase = bn + wc * 64;   // wave-uniform, 64-aligned -> one head
    if (colbase < 2048) {               // Q region (RoPE + scale)
      const int h = colbase >> 6;
#pragma unroll
      for (int m = 0; m < 8; ++m) {
#pragma unroll
        for (int r = 0; r < 4; ++r) {
          const int srow = bm + wr * 128 + m * 16 + l4 * 4 + r;
          const int b = srow >> 11, s = srow & 2047;
          const float* cs = cosb + s * HD_;
          const float* sn = sinb + s * HD_;
          bf16_t* qp = Q + ((int64_t)(b * H_ + h) * S_ + s) * HD_;
#pragma unroll
          for (int n = 0; n < 4; ++n) {
            const int d = n * 16 + l15;
            const float sgn = (n & 2) ? 1.f : -1.f;
            float o = (acc[m][n][r] * cs[d] + sgn * acc[m][n ^ 2][r] * sn[d]) * QSCALE;
            qp[d] = (bf16_t)o;
          }
        }
      }
    } else if (colbase < 2560) {        // K region (RoPE)
      const int kvh = (colbase - 2048) >> 6;
#pragma unroll
      for (int m = 0; m < 8; ++m) {
#pragma unroll
        for (int r = 0; r < 4; ++r) {
          const int srow = bm + wr * 128 + m * 16 + l4 * 4 + r;
          const int b = srow >> 11, s = srow & 2047;
          const float* cs = cosb + s * HD_;
          const float* sn = sinb + s * HD_;
          bf16_t* kp = Kr + ((int64_t)(b * KV_ + kvh) * S_ + s) * HD_;
#pragma unroll
          for (int n = 0; n < 4; ++n) {
            const int d = n * 16 + l15;
            const float sgn = (n & 2) ? 1.f : -1.f;
            float o = acc[m][n][r] * cs[d] + sgn * acc[m][n ^ 2][r] * sn[d];
            kp[d] = (bf16_t)o;
          }
        }
      }
    } else {                            // V region (row-major, coalesced)
      const int ccb = colbase - 2560;
#pragma unroll
      for (int m = 0; m < 8; ++m) {
#pragma unroll
        for (int r = 0; r < 4; ++r) {
          const int srow = bm + wr * 128 + m * 16 + l4 * 4 + r;
          bf16_t* vp = Vbuf + (int64_t)srow * 512 + ccb;
#pragma unroll
          for (int n = 0; n < 4; ++n)
            vp[n * 16 + l15] = (bf16_t)acc[m][n][r];
        }
      }
    }
  }
}

// ---------------- flash attention: 3-deep counted-vmcnt LDS pipeline ----------------
// grid (16 = b*8+kvh, 32 = qc). 8 waves share K/V tiles; wave w -> head kvh*4+(w&3),
// q-rows qc*64+(w>>2)*32. Per iter: vmcnt(2) [loads issued 2 tiles ago] -> barrier ->
// stage t+2 -> compute t. Uniform load count per wave (clamped stage source).
#define SHIFT_ 8.0f
__global__ __launch_bounds__(512) void attn6(const bf16_t* __restrict__ Q,
                                             const bf16_t* __restrict__ Kr,
                                             const bf16_t* __restrict__ Vt,
                                             bf16_t* __restrict__ AO) {
  const int bk = blockIdx.x;
  const int b = bk >> 3, kvh = bk & 7;
  const int qc = 31 - (int)blockIdx.y;    // longest blocks dispatched first
  const int tid = threadIdx.x;
  const int w = tid >> 6, lane = tid & 63;
  const int l31 = lane & 31, hi = lane >> 5;
  const int h = kvh * 4 + (w & 3);
  const int q0w = qc * 64 + (w >> 2) * 32;

  __shared__ __align__(16) bf16_t Ks[3][64 * 64];   // [buf][kv][d] (swizzled granules)
  __shared__ __align__(16) bf16_t Vs[3][64 * 64];   // [buf][d][kv]

  const bf16_t* Qb = Q  + ((int64_t)(b * H_ + h) * S_ + q0w) * HD_;
  const bf16_t* Kg = Kr + (int64_t)(b * KV_ + kvh) * S_ * HD_;
  const bf16_t* Vg = Vt + (int64_t)(b * KV_ + kvh) * HD_ * S_;   // [d][s]

  const int rL = (w << 3) + (lane >> 3);
  const int sgr = ((lane & 7) ^ (rL & 7)) << 3;     // element offset
  const bf16_t* Ksrc = Kg + rL * HD_ + sgr;
  const bf16_t* Vsrc = Vg + (int64_t)rL * S_ + sgr;
  char* KsDst = (char*)&Ks[0][0] + w * 1024;
  char* VsDst = (char*)&Vs[0][0] + w * 1024;

  const int NT = qc + 1;                  // 64-kv tiles

  auto stage = [&](int t) {               // always issues exactly 2 loads (uniform vmcnt)
    const int tc = (t < NT) ? t : (NT - 1);
    const int bufo = (t % 3) * 8192;
    gload_lds16(Ksrc + tc * 64 * HD_, KsDst + bufo);
    gload_lds16(Vsrc + tc * 64,      VsDst + bufo);
  };

  bf16x8 qf[4];
#pragma unroll
  for (int ds = 0; ds < 4; ++ds)
    qf[ds] = *(const bf16x8*)(Qb + l31 * HD_ + ds * 16 + hi * 8);

  f32x16 accO0 = {}, accO1 = {};          // O^T partial: rows d 0-31/32-63, col q = l31
  float lhalf = 0.f;
  const int xorb = l31 & 7;

  const char* KsB = (const char*)&Ks[0][0];
  const char* VsB = (const char*)&Vs[0][0];

  const f32x16 sinit = {SHIFT_ > 0 ? -SHIFT_ : 0.f, -SHIFT_, -SHIFT_, -SHIFT_,
                        -SHIFT_, -SHIFT_, -SHIFT_, -SHIFT_,
                        -SHIFT_, -SHIFT_, -SHIFT_, -SHIFT_,
                        -SHIFT_, -SHIFT_, -SHIFT_, -SHIFT_};

  stage(0);
  stage(1);

  for (int t = 0; t < NT; ++t) {
    asm volatile("s_waitcnt vmcnt(2)" ::: "memory");
    __syncthreads();
    stage(t + 2);
    const int curo = (t % 3) * 8192;
#pragma unroll
    for (int sub = 0; sub < 2; ++sub) {
      const int kvbase = t * 64 + sub * 32;
      if (kvbase <= q0w) {
        const bool diag = (kvbase == q0w);
        const char* Kbase = KsB + curo + (sub * 32 + l31) * 128;
        f32x16 sacc = sinit;              // fold -SHIFT into MFMA C-init
        __builtin_amdgcn_s_setprio(1);
#pragma unroll
        for (int ds = 0; ds < 4; ++ds) {
          bf16x8 kf = *(const bf16x8*)(Kbase + ((((ds << 1) + hi) ^ xorb) << 4));
          sacc = __builtin_amdgcn_mfma_f32_32x32x16_bf16(kf, qf[ds], sacc, 0, 0, 0);
        }
        __builtin_amdgcn_s_setprio(0);
        float p[16];
#pragma unroll
        for (int r = 0; r < 16; ++r) {
          float sc = sacc[r];
          if (diag) {
            int kvpos = (r & 3) + 8 * (r >> 2) + 4 * hi;
            if (kvpos > l31) sc = -1e30f;
          }
          p[r] = __builtin_amdgcn_exp2f(sc);
        }
        float t0 = (p[0] + p[1]) + (p[2] + p[3]);
        float t1 = (p[4] + p[5]) + (p[6] + p[7]);
        float t2 = (p[8] + p[9]) + (p[10] + p[11]);
        float t3 = (p[12] + p[13]) + (p[14] + p[15]);
        lhalf += (t0 + t1) + (t2 + t3);
        u32 pk[8];
#pragma unroll
        for (int i = 0; i < 8; ++i) pk[i] = pkbf(p[2*i], p[2*i+1]);
        u32 a0 = pk[0], b0 = pk[2]; pl32swap(a0, b0);
        u32 a1 = pk[1], b1 = pk[3]; pl32swap(a1, b1);
        u32 a2 = pk[4], b2 = pk[6]; pl32swap(a2, b2);
        u32 a3 = pk[5], b3 = pk[7]; pl32swap(a3, b3);
        bf16x8 pf0 = __builtin_bit_cast(bf16x8, (u32x4){a0, a1, b0, b1});
        bf16x8 pf1 = __builtin_bit_cast(bf16x8, (u32x4){a2, a3, b2, b3});
        const char* Vb0 = VsB + curo + l31 * 128;
        const char* Vb1 = VsB + curo + (32 + l31) * 128;
        const int c0 = (sub << 2) + hi;
        const int c1 = (sub << 2) + 2 + hi;
        bf16x8 v00 = *(const bf16x8*)(Vb0 + ((c0 ^ xorb) << 4));
        bf16x8 v01 = *(const bf16x8*)(Vb0 + ((c1 ^ xorb) << 4));
        bf16x8 v10 = *(const bf16x8*)(Vb1 + ((c0 ^ xorb) << 4));
        bf16x8 v11 = *(const bf16x8*)(Vb1 + ((c1 ^ xorb) << 4));
        __builtin_amdgcn_s_setprio(1);
        accO0 = __builtin_amdgcn_mfma_f32_32x32x16_bf16(v00, pf0, accO0, 0, 0, 0);
        accO1 = __builtin_amdgcn_mfma_f32_32x32x16_bf16(v10, pf0, accO1, 0, 0, 0);
        accO0 = __builtin_amdgcn_mfma_f32_32x32x16_bf16(v01, pf1, accO0, 0, 0, 0);
        accO1 = __builtin_amdgcn_mfma_f32_32x32x16_bf16(v11, pf1, accO1, 0, 0, 0);
        __builtin_amdgcn_s_setprio(0);
      }
    }
  }

  // drain outstanding gload_lds before workgroup exit (LDS could be reallocated)
  asm volatile("s_waitcnt vmcnt(0)" ::: "memory");

  float lrun = lhalf + __shfl_xor(lhalf, 32);
  const float rl = 1.f / lrun;
  const int64_t row = (int64_t)(b * S_ + q0w + l31);
#pragma unroll
  for (int dt = 0; dt < 2; ++dt) {
#pragma unroll
    for (int g = 0; g < 4; ++g) {
      bf16x4 ov;
#pragma unroll
      for (int j = 0; j < 4; ++j) {
        float val = (dt ? accO1[4*g + j] : accO0[4*g + j]) * rl;
        ov[j] = (bf16_t)val;
      }
      const int d0 = dt * 32 + g * 8 + hi * 4;
      *(bf16x4*)(AO + row * D_ + h * HD_ + d0) = ov;
    }
  }
}

// ---------------- launcher ----------------
extern "C" void kernel_launch(void* const* d_in, const int* in_sizes, int n_in,
                              void* d_out, int out_size, void* d_ws, size_t ws_size,
                              hipStream_t stream) {
  const float* x    = (const float*)d_in[0];
  const float* cosb = (const float*)d_in[1];
  const float* sinb = (const float*)d_in[2];
  const float* Wq   = (const float*)d_in[3];
  const float* Wk   = (const float*)d_in[4];
  const float* Wv   = (const float*)d_in[5];
  const float* Wo   = (const float*)d_in[6];
  float* out = (float*)d_out;

  bf16_t* ws = (bf16_t*)d_ws;
  size_t o = 0;
  bf16_t* xb    = ws + o; o += (size_t)4096 * 2048;
  bf16_t* Wqkvt = ws + o; o += (size_t)3072 * 2048;
  bf16_t* Wot   = ws + o; o += (size_t)2048 * 2048;
  bf16_t* Qr    = ws + o; o += (size_t)B_ * H_ * S_ * HD_;
  bf16_t* Krb   = ws + o; o += (size_t)B_ * KV_ * S_ * HD_;
  bf16_t* Vtb   = ws + o; o += (size_t)B_ * KV_ * S_ * HD_;
  bf16_t* Vbuf  = ws + o; o += (size_t)B_ * S_ * 512;
  bf16_t* AO    = ws + o; o += (size_t)4096 * 2048;

  cvt_f32_bf16<<<(8388608/4 + 255)/256, 256, 0, stream>>>(x, xb, 8388608/4);
  transpose_cvt<<<dim3(2048/32, 2048/32), dim3(32, 8), 0, stream>>>(Wq, Wqkvt, 2048, 0);
  transpose_cvt<<<dim3(512/32, 2048/32),  dim3(32, 8), 0, stream>>>(Wk, Wqkvt, 512, 2048);
  transpose_cvt<<<dim3(512/32, 2048/32),  dim3(32, 8), 0, stream>>>(Wv, Wqkvt, 512, 2560);
  transpose_cvt<<<dim3(2048/32, 2048/32), dim3(32, 8), 0, stream>>>(Wo, Wot, 2048, 0);
  // fused QKV projection + RoPE + scatter (256x256, dedup'd LDS reads)
  gemm256<256, 1><<<dim3(3072/256, 4096/256), 512, 0, stream>>>(
      xb, Wqkvt, cosb, sinb, Qr, Krb, Vbuf, nullptr, 3072, 2048);
  // V transpose to [b][d][s]
  v_transpose<<<dim3(16, 64, 2), dim3(32, 8), 0, stream>>>(Vbuf, Vtb);
  // 3-deep counted-vmcnt attention
  attn6<<<dim3(16, 32), 512, 0, stream>>>(Qr, Krb, Vtb, AO);
  // output projection -> f32 (256x128, 256 blocks = 1/CU)
  gemm256<128, 0><<<dim3(2048/128, 4096/256), 512, 0, stream>>>(
      AO, Wot, nullptr, nullptr, nullptr, nullptr, nullptr, out, 2048, 2048);
}

// Round 10
// 180.414 us; speedup vs baseline: 1.6927x; 1.0375x over previous
//
#include <hip/hip_runtime.h>
#include <hip/hip_bf16.h>
#include <stdint.h>

#define B_ 2
#define S_ 2048
#define D_ 2048
#define H_ 32
#define KV_ 8
#define HD_ 64
#define NQKV 3072   // D + 2*KV*HD

typedef __bf16 bf16_t;
typedef __bf16 bf16x8 __attribute__((ext_vector_type(8)));
typedef __bf16 bf16x4 __attribute__((ext_vector_type(4)));
typedef float  f32x4  __attribute__((ext_vector_type(4)));
typedef float  f32x16 __attribute__((ext_vector_type(16)));
typedef unsigned int u32;
typedef u32 u32x4 __attribute__((ext_vector_type(4)));

typedef const __attribute__((address_space(1))) uint32_t* gp1_t;
typedef __attribute__((address_space(3))) uint32_t* lp3_t;

// async global->LDS, 16B per lane. LDS dest is wave-uniform base + lane*16.
__device__ inline void gload_lds16(const void* g, void* l) {
  __builtin_amdgcn_global_load_lds((gp1_t)(uintptr_t)g, (lp3_t)(uint32_t)(uintptr_t)l,
                                   16, 0, 0);
}

__device__ inline u32 pkbf(float a, float b) {
  union { bf16_t h[2]; u32 u; } v;
  v.h[0] = (bf16_t)a; v.h[1] = (bf16_t)b;
  return v.u;
}

// v_permlane32_swap_b32: a = [a_lo, b_lo], b = [a_hi, b_hi]
__device__ inline void pl32swap(u32 &a, u32 &b) {
  asm("v_permlane32_swap_b32 %0, %1" : "+v"(a), "+v"(b));
}

// ---------------- converts ----------------
__global__ void cvt_f32_bf16(const float* __restrict__ in, bf16_t* __restrict__ out, int n4) {
  int i = blockIdx.x * blockDim.x + threadIdx.x;
  if (i < n4) {
    float4 v = ((const float4*)in)[i];
    bf16x4 o;
    o[0] = (bf16_t)v.x; o[1] = (bf16_t)v.y; o[2] = (bf16_t)v.z; o[3] = (bf16_t)v.w;
    ((bf16x4*)out)[i] = o;
  }
}

// transpose + cast: out[row_off + c][r] = in[r][c]
__global__ void transpose_cvt(const float* __restrict__ in, bf16_t* __restrict__ out,
                              int C, int row_off) {
  __shared__ float t[32][33];
  int tx = threadIdx.x, ty = threadIdx.y;       // (32,8)
  int c0 = blockIdx.x * 32, r0 = blockIdx.y * 32;
#pragma unroll
  for (int j = 0; j < 4; ++j)
    t[ty + j*8][tx] = in[(int64_t)(r0 + ty + j*8) * C + c0 + tx];
  __syncthreads();
#pragma unroll
  for (int j = 0; j < 4; ++j)
    out[(int64_t)(row_off + c0 + ty + j*8) * 2048 + r0 + tx] = (bf16_t)t[tx][ty + j*8];
}

// Vbuf[b][s][cc] -> Vt[b][cc][s]  (LDS-tiled transpose, coalesced both sides)
__global__ void v_transpose(const bf16_t* __restrict__ Vbuf, bf16_t* __restrict__ Vt) {
  __shared__ bf16_t t[32][34];
  const int tx = threadIdx.x, ty = threadIdx.y;   // (32,8)
  const int c0 = blockIdx.x * 32;                 // cc within 512
  const int s0 = blockIdx.y * 32;
  const int b  = blockIdx.z;
#pragma unroll
  for (int j = 0; j < 4; ++j)
    t[ty + j*8][tx] = Vbuf[(int64_t)(b * S_ + s0 + ty + j*8) * 512 + c0 + tx];
  __syncthreads();
#pragma unroll
  for (int j = 0; j < 4; ++j)
    Vt[(int64_t)(b * 512 + c0 + ty + j*8) * S_ + s0 + tx] = t[tx][ty + j*8];
}

// ---------------- 256-row deep-pipelined GEMM (dedup'd LDS reads) ----------------
#define QSCALE 0.18033688011112042f
template <int BN, int EPI>
__global__ __launch_bounds__(512, 2) void gemm256(const bf16_t* __restrict__ A,
                                                  const bf16_t* __restrict__ Bt,
                                                  const float* __restrict__ cosb,
                                                  const float* __restrict__ sinb,
                                                  bf16_t* __restrict__ Q,
                                                  bf16_t* __restrict__ Kr,
                                                  bf16_t* __restrict__ Vbuf,
                                                  float* __restrict__ Cout,
                                                  int N, int K) {
  constexpr int NB = BN / 64;          // B stage loads per tile
  constexpr int LT = 4 + NB;           // total stage loads per tile
  constexpr int WCOLS = BN / 4;        // per-wave cols
  constexpr int NF = WCOLS / 16;       // per-wave n fragments (4 or 2)

  __shared__ bf16_t As[2][256 * 64];
  __shared__ bf16_t Bs[2][BN * 64];

  const int tid = threadIdx.x;
  const int w = tid >> 6, lane = tid & 63;
  const int l15 = lane & 15, l4 = lane >> 4;
  const int wr = w >> 2, wc = w & 3;
  const int bm = blockIdx.y * 256, bn = blockIdx.x * BN;

  const int rw = w * 8 + (lane >> 3);
  const int srcg = ((lane & 7) ^ ((lane >> 3) & 7)) << 3;   // element offset
  const bf16_t* PA[4];
  const bf16_t* PB[NB];
#pragma unroll
  for (int L = 0; L < 4; ++L)
    PA[L] = A + (int64_t)(bm + L * 64 + rw) * K + srcg;
#pragma unroll
  for (int L = 0; L < NB; ++L)
    PB[L] = Bt + (int64_t)(bn + L * 64 + rw) * K + srcg;

  const int NK = K >> 6;
  const int xr = l15 & 7;
  const int g0 = (l4 ^ xr) << 3;          // kk=0 slot, element offset
  const int g1 = ((4 + l4) ^ xr) << 3;    // kk=1 slot

  f32x4 acc[8][NF] = {};

#pragma unroll
  for (int s = 0; s < LT; ++s) {
    if (s < 4) gload_lds16(PA[s], &As[0][s * 4096 + w * 512]);
    else       gload_lds16(PB[s - 4], &Bs[0][(s - 4) * 4096 + w * 512]);
  }
  asm volatile("s_waitcnt vmcnt(0)" ::: "memory");
  __syncthreads();

  for (int t = 0; t < NK; ++t) {
    const int p = t & 1;
    const bool more = (t + 1) < NK;
    const int toff = (t + 1) << 6;
    const bf16_t* Ab = &As[p][0];
    const bf16_t* Bb = &Bs[p][0];

    bf16x8 ball[NF][2];
#pragma unroll
    for (int nn = 0; nn < NF; ++nn) {
      const int rb = wc * WCOLS + nn * 16 + l15;
      ball[nn][0] = *(const bf16x8*)(Bb + rb * 64 + g0);
      ball[nn][1] = *(const bf16x8*)(Bb + rb * 64 + g1);
    }

#pragma unroll
    for (int mh = 0; mh < 2; ++mh) {
      if (more) {
        const int s0 = mh * (LT / 2), s1 = s0 + LT / 2;
#pragma unroll
        for (int s = s0; s < s1; ++s) {
          if (s < 4) gload_lds16(PA[s] + toff, &As[p ^ 1][s * 4096 + w * 512]);
          else       gload_lds16(PB[s - 4] + toff, &Bs[p ^ 1][(s - 4) * 4096 + w * 512]);
        }
      }
      bf16x8 af[4][2];
#pragma unroll
      for (int mm = 0; mm < 4; ++mm) {
        const int ra = wr * 128 + (mh * 4 + mm) * 16 + l15;
        af[mm][0] = *(const bf16x8*)(Ab + ra * 64 + g0);
        af[mm][1] = *(const bf16x8*)(Ab + ra * 64 + g1);
      }
      __builtin_amdgcn_s_setprio(1);
#pragma unroll
      for (int mm = 0; mm < 4; ++mm)
#pragma unroll
        for (int nn = 0; nn < NF; ++nn) {
          acc[mh*4+mm][nn] = __builtin_amdgcn_mfma_f32_16x16x32_bf16(
              af[mm][0], ball[nn][0], acc[mh*4+mm][nn], 0, 0, 0);
          acc[mh*4+mm][nn] = __builtin_amdgcn_mfma_f32_16x16x32_bf16(
              af[mm][1], ball[nn][1], acc[mh*4+mm][nn], 0, 0, 0);
        }
      __builtin_amdgcn_s_setprio(0);
    }
    if (more) {
      asm volatile("s_waitcnt vmcnt(0)" ::: "memory");
      __syncthreads();
    }
  }

  if constexpr (EPI == 0) {             // plain float C
#pragma unroll
    for (int m = 0; m < 8; ++m) {
      const int row = bm + wr * 128 + m * 16 + l4 * 4;
#pragma unroll
      for (int n = 0; n < NF; ++n) {
        const int col = bn + wc * WCOLS + n * 16 + l15;
#pragma unroll
        for (int r = 0; r < 4; ++r)
          Cout[(int64_t)(row + r) * N + col] = acc[m][n][r];
      }
    }
  } else {                              // fused RoPE / scatter epilogue (BN=256)
    const int colbase = bn + wc * 64;   // wave-uniform, 64-aligned -> one head
    if (colbase < 2048) {               // Q region (RoPE + scale)
      const int h = colbase >> 6;
#pragma unroll
      for (int m = 0; m < 8; ++m) {
#pragma unroll
        for (int r = 0; r < 4; ++r) {
          const int srow = bm + wr * 128 + m * 16 + l4 * 4 + r;
          const int b = srow >> 11, s = srow & 2047;
          const float* cs = cosb + s * HD_;
          const float* sn = sinb + s * HD_;
          bf16_t* qp = Q + ((int64_t)(b * H_ + h) * S_ + s) * HD_;
#pragma unroll
          for (int n = 0; n < 4; ++n) {
            const int d = n * 16 + l15;
            const float sgn = (n & 2) ? 1.f : -1.f;
            float o = (acc[m][n][r] * cs[d] + sgn * acc[m][n ^ 2][r] * sn[d]) * QSCALE;
            qp[d] = (bf16_t)o;
          }
        }
      }
    } else if (colbase < 2560) {        // K region (RoPE)
      const int kvh = (colbase - 2048) >> 6;
#pragma unroll
      for (int m = 0; m < 8; ++m) {
#pragma unroll
        for (int r = 0; r < 4; ++r) {
          const int srow = bm + wr * 128 + m * 16 + l4 * 4 + r;
          const int b = srow >> 11, s = srow & 2047;
          const float* cs = cosb + s * HD_;
          const float* sn = sinb + s * HD_;
          bf16_t* kp = Kr + ((int64_t)(b * KV_ + kvh) * S_ + s) * HD_;
#pragma unroll
          for (int n = 0; n < 4; ++n) {
            const int d = n * 16 + l15;
            const float sgn = (n & 2) ? 1.f : -1.f;
            float o = acc[m][n][r] * cs[d] + sgn * acc[m][n ^ 2][r] * sn[d];
            kp[d] = (bf16_t)o;
          }
        }
      }
    } else {                            // V region (row-major, coalesced)
      const int ccb = colbase - 2560;
#pragma unroll
      for (int m = 0; m < 8; ++m) {
#pragma unroll
        for (int r = 0; r < 4; ++r) {
          const int srow = bm + wr * 128 + m * 16 + l4 * 4 + r;
          bf16_t* vp = Vbuf + (int64_t)srow * 512 + ccb;
#pragma unroll
          for (int n = 0; n < 4; ++n)
            vp[n * 16 + l15] = (bf16_t)acc[m][n][r];
        }
      }
    }
  }
}

// ---------------- flash attention: paired-chunk waves, 2x K/V reuse ----------------
// grid (16 = b*8+kvh, 32 = y). 256 thr = 4 waves; wave w = head kvh*4+w, owning TWO
// 32-row q-chunks {y, 63-y} (constant 65 chunk-subs/wave -> all 512 blocks equal).
// K/V 64-kv tiles staged in LDS by the 4 waves (3-deep, counted vmcnt(4), granule-XOR
// swizzle both sides); each K/V fragment feeds both chunks' MFMAs.
#define SHIFT_ 8.0f
__global__ __launch_bounds__(256, 2) void attn7(const bf16_t* __restrict__ Q,
                                                const bf16_t* __restrict__ Kr,
                                                const bf16_t* __restrict__ Vt,
                                                bf16_t* __restrict__ AO) {
  const int bk = blockIdx.x;
  const int b = bk >> 3, kvh = bk & 7;
  const int y = blockIdx.y;               // 0..31
  const int q0A = y * 32, q0B = (63 - y) * 32;
  const int tid = threadIdx.x;
  const int w = tid >> 6, lane = tid & 63;
  const int l31 = lane & 31, hi = lane >> 5;
  const int h = kvh * 4 + w;

  __shared__ __align__(16) bf16_t Ks[3][64 * 64];   // [buf][kv][d] (swizzled granules)
  __shared__ __align__(16) bf16_t Vs[3][64 * 64];   // [buf][d][kv]

  const bf16_t* Kg = Kr + (int64_t)(b * KV_ + kvh) * S_ * HD_;
  const bf16_t* Vg = Vt + (int64_t)(b * KV_ + kvh) * HD_ * S_;   // [d][s]

  // staging: 4 waves x 2 passes of 32 rows; row = p*32 + w*8 + lane>>3
  const int rL = (w << 3) + (lane >> 3);
  const int sgr = ((lane & 7) ^ (rL & 7)) << 3;     // element offset
  const bf16_t* Ksrc = Kg + (int64_t)rL * HD_ + sgr;
  const bf16_t* Vsrc = Vg + (int64_t)rL * S_ + sgr;

  const int NT = (63 - y) / 2 + 1;        // 64-kv tiles (chunk B reach)

  auto stage = [&](int t) {               // exactly 4 loads per wave (uniform vmcnt)
    const int tc = (t < NT) ? t : (NT - 1);
    char* Kd = (char*)Ks + (t % 3) * 8192 + w * 1024;
    char* Vd = (char*)Vs + (t % 3) * 8192 + w * 1024;
    gload_lds16(Ksrc + (int64_t)tc * 64 * HD_, Kd);
    gload_lds16(Ksrc + (int64_t)(tc * 64 + 32) * HD_, Kd + 4096);
    gload_lds16(Vsrc + tc * 64, Vd);
    gload_lds16(Vsrc + (int64_t)32 * S_ + tc * 64, Vd + 4096);
  };

  const bf16_t* QbA = Q + ((int64_t)(b * H_ + h) * S_ + q0A) * HD_;
  const bf16_t* QbB = Q + ((int64_t)(b * H_ + h) * S_ + q0B) * HD_;
  bf16x8 qfA[4], qfB[4];
#pragma unroll
  for (int ds = 0; ds < 4; ++ds) {
    qfA[ds] = *(const bf16x8*)(QbA + l31 * HD_ + ds * 16 + hi * 8);
    qfB[ds] = *(const bf16x8*)(QbB + l31 * HD_ + ds * 16 + hi * 8);
  }

  f32x16 aA0 = {}, aA1 = {}, aB0 = {}, aB1 = {};    // O^T partials per chunk
  float lhA = 0.f, lhB = 0.f;
  const int xorb = l31 & 7;

  const f32x16 sinit = {-SHIFT_, -SHIFT_, -SHIFT_, -SHIFT_,
                        -SHIFT_, -SHIFT_, -SHIFT_, -SHIFT_,
                        -SHIFT_, -SHIFT_, -SHIFT_, -SHIFT_,
                        -SHIFT_, -SHIFT_, -SHIFT_, -SHIFT_};

  auto softmax_pack = [&](const f32x16 &sacc, bool diag, float &lh,
                          bf16x8 &pf0, bf16x8 &pf1) {
    float p[16];
#pragma unroll
    for (int r = 0; r < 16; ++r) {
      float sc = sacc[r];
      if (diag) {
        int kvpos = (r & 3) + 8 * (r >> 2) + 4 * hi;
        if (kvpos > l31) sc = -1e30f;
      }
      p[r] = __builtin_amdgcn_exp2f(sc);
    }
    float t0 = (p[0] + p[1]) + (p[2] + p[3]);
    float t1 = (p[4] + p[5]) + (p[6] + p[7]);
    float t2 = (p[8] + p[9]) + (p[10] + p[11]);
    float t3 = (p[12] + p[13]) + (p[14] + p[15]);
    lh += (t0 + t1) + (t2 + t3);
    u32 pk[8];
#pragma unroll
    for (int i = 0; i < 8; ++i) pk[i] = pkbf(p[2*i], p[2*i+1]);
    u32 a0 = pk[0], b0 = pk[2]; pl32swap(a0, b0);
    u32 a1 = pk[1], b1 = pk[3]; pl32swap(a1, b1);
    u32 a2 = pk[4], b2 = pk[6]; pl32swap(a2, b2);
    u32 a3 = pk[5], b3 = pk[7]; pl32swap(a3, b3);
    pf0 = __builtin_bit_cast(bf16x8, (u32x4){a0, a1, b0, b1});
    pf1 = __builtin_bit_cast(bf16x8, (u32x4){a2, a3, b2, b3});
  };

  stage(0);
  stage(1);

  for (int t = 0; t < NT; ++t) {
    asm volatile("s_waitcnt vmcnt(4)" ::: "memory");
    __syncthreads();
    stage(t + 2);
    const char* KsB = (const char*)Ks + (t % 3) * 8192;
    const char* VsB = (const char*)Vs + (t % 3) * 8192;
#pragma unroll
    for (int sub = 0; sub < 2; ++sub) {
      const int kvbase = t * 64 + sub * 32;
      if (kvbase <= q0B) {
        const bool actA = (kvbase <= q0A);
        // ---- shared K fragments ----
        const char* Kbase = KsB + (sub * 32 + l31) * 128;
        bf16x8 kf[4];
#pragma unroll
        for (int ds = 0; ds < 4; ++ds)
          kf[ds] = *(const bf16x8*)(Kbase + ((((ds << 1) + hi) ^ xorb) << 4));
        // ---- QK for both chunks (independent chains) ----
        f32x16 sA = sinit, sB = sinit;
        __builtin_amdgcn_s_setprio(1);
#pragma unroll
        for (int ds = 0; ds < 4; ++ds)
          sB = __builtin_amdgcn_mfma_f32_32x32x16_bf16(kf[ds], qfB[ds], sB, 0, 0, 0);
        if (actA) {
#pragma unroll
          for (int ds = 0; ds < 4; ++ds)
            sA = __builtin_amdgcn_mfma_f32_32x32x16_bf16(kf[ds], qfA[ds], sA, 0, 0, 0);
        }
        __builtin_amdgcn_s_setprio(0);
        // ---- softmax + pack per chunk ----
        bf16x8 pA0, pA1, pB0, pB1;
        softmax_pack(sB, kvbase == q0B, lhB, pB0, pB1);
        if (actA) softmax_pack(sA, kvbase == q0A, lhA, pA0, pA1);
        // ---- shared V fragments ----
        const char* Vb0 = VsB + l31 * 128;
        const char* Vb1 = VsB + (32 + l31) * 128;
        const int c0 = (sub << 2) + hi;
        const int c1 = c0 + 2;
        bf16x8 v00 = *(const bf16x8*)(Vb0 + ((c0 ^ xorb) << 4));
        bf16x8 v01 = *(const bf16x8*)(Vb0 + ((c1 ^ xorb) << 4));
        bf16x8 v10 = *(const bf16x8*)(Vb1 + ((c0 ^ xorb) << 4));
        bf16x8 v11 = *(const bf16x8*)(Vb1 + ((c1 ^ xorb) << 4));
        // ---- PV for both chunks ----
        __builtin_amdgcn_s_setprio(1);
        aB0 = __builtin_amdgcn_mfma_f32_32x32x16_bf16(v00, pB0, aB0, 0, 0, 0);
        aB1 = __builtin_amdgcn_mfma_f32_32x32x16_bf16(v10, pB0, aB1, 0, 0, 0);
        aB0 = __builtin_amdgcn_mfma_f32_32x32x16_bf16(v01, pB1, aB0, 0, 0, 0);
        aB1 = __builtin_amdgcn_mfma_f32_32x32x16_bf16(v11, pB1, aB1, 0, 0, 0);
        if (actA) {
          aA0 = __builtin_amdgcn_mfma_f32_32x32x16_bf16(v00, pA0, aA0, 0, 0, 0);
          aA1 = __builtin_amdgcn_mfma_f32_32x32x16_bf16(v10, pA0, aA1, 0, 0, 0);
          aA0 = __builtin_amdgcn_mfma_f32_32x32x16_bf16(v01, pA1, aA0, 0, 0, 0);
          aA1 = __builtin_amdgcn_mfma_f32_32x32x16_bf16(v11, pA1, aA1, 0, 0, 0);
        }
        __builtin_amdgcn_s_setprio(0);
      }
    }
  }

  // drain outstanding gload_lds before workgroup exit
  asm volatile("s_waitcnt vmcnt(0)" ::: "memory");

  auto epi = [&](const f32x16 &a0, const f32x16 &a1, float lh, int q0) {
    float l = lh + __shfl_xor(lh, 32);
    const float rl = 1.f / l;
    const int64_t row = (int64_t)(b * S_ + q0 + l31);
#pragma unroll
    for (int dt = 0; dt < 2; ++dt) {
#pragma unroll
      for (int g = 0; g < 4; ++g) {
        bf16x4 ov;
#pragma unroll
        for (int j = 0; j < 4; ++j) {
          float val = (dt ? a1[4*g + j] : a0[4*g + j]) * rl;
          ov[j] = (bf16_t)val;
        }
        const int d0 = dt * 32 + g * 8 + hi * 4;
        *(bf16x4*)(AO + row * D_ + h * HD_ + d0) = ov;
      }
    }
  };
  epi(aA0, aA1, lhA, q0A);
  epi(aB0, aB1, lhB, q0B);
}

// ---------------- launcher ----------------
extern "C" void kernel_launch(void* const* d_in, const int* in_sizes, int n_in,
                              void* d_out, int out_size, void* d_ws, size_t ws_size,
                              hipStream_t stream) {
  const float* x    = (const float*)d_in[0];
  const float* cosb = (const float*)d_in[1];
  const float* sinb = (const float*)d_in[2];
  const float* Wq   = (const float*)d_in[3];
  const float* Wk   = (const float*)d_in[4];
  const float* Wv   = (const float*)d_in[5];
  const float* Wo   = (const float*)d_in[6];
  float* out = (float*)d_out;

  bf16_t* ws = (bf16_t*)d_ws;
  size_t o = 0;
  bf16_t* xb    = ws + o; o += (size_t)4096 * 2048;
  bf16_t* Wqkvt = ws + o; o += (size_t)3072 * 2048;
  bf16_t* Wot   = ws + o; o += (size_t)2048 * 2048;
  bf16_t* Qr    = ws + o; o += (size_t)B_ * H_ * S_ * HD_;
  bf16_t* Krb   = ws + o; o += (size_t)B_ * KV_ * S_ * HD_;
  bf16_t* Vtb   = ws + o; o += (size_t)B_ * KV_ * S_ * HD_;
  bf16_t* Vbuf  = ws + o; o += (size_t)B_ * S_ * 512;
  bf16_t* AO    = ws + o; o += (size_t)4096 * 2048;

  cvt_f32_bf16<<<(8388608/4 + 255)/256, 256, 0, stream>>>(x, xb, 8388608/4);
  transpose_cvt<<<dim3(2048/32, 2048/32), dim3(32, 8), 0, stream>>>(Wq, Wqkvt, 2048, 0);
  transpose_cvt<<<dim3(512/32, 2048/32),  dim3(32, 8), 0, stream>>>(Wk, Wqkvt, 512, 2048);
  transpose_cvt<<<dim3(512/32, 2048/32),  dim3(32, 8), 0, stream>>>(Wv, Wqkvt, 512, 2560);
  transpose_cvt<<<dim3(2048/32, 2048/32), dim3(32, 8), 0, stream>>>(Wo, Wot, 2048, 0);
  // fused QKV projection + RoPE + scatter (256x256, dedup'd LDS reads)
  gemm256<256, 1><<<dim3(3072/256, 4096/256), 512, 0, stream>>>(
      xb, Wqkvt, cosb, sinb, Qr, Krb, Vbuf, nullptr, 3072, 2048);
  // V transpose to [b][d][s]
  v_transpose<<<dim3(16, 64, 2), dim3(32, 8), 0, stream>>>(Vbuf, Vtb);
  // paired-chunk attention (4-wave blocks, 2x K/V reuse, equal-work blocks)
  attn7<<<dim3(16, 32), 256, 0, stream>>>(Qr, Krb, Vtb, AO);
  // output projection -> f32 (256x128, 256 blocks = 1/CU)
  gemm256<128, 0><<<dim3(2048/128, 4096/256), 512, 0, stream>>>(
      AO, Wot, nullptr, nullptr, nullptr, nullptr, nullptr, out, 2048, 2048);
}